// Round 1
// baseline (414.076 us; speedup 1.0000x reference)
//
#include <hip/hip_runtime.h>

// ---------------------------------------------------------------------------
// LinearSelfAttention: B=4 T=4096 DIM=1024 H=16 E=64 BUCKET=64 U=64
// out = ( causal_linear_attn( softmax(xWq), elu(xWk)+1, xWv ) ) Wo + bo
// ---------------------------------------------------------------------------

#define T_LEN 4096
#define DIMN  1024
#define NHEAD 16
#define NB    4
#define MROWS (NB * T_LEN)   // 16384

typedef float f32x4 __attribute__((ext_vector_type(4)));
typedef short s16x8 __attribute__((ext_vector_type(8)));
typedef short s16x4 __attribute__((ext_vector_type(4)));
using u16 = unsigned short;

__device__ __forceinline__ u16 f2bf(float f) {
  unsigned int u = __float_as_uint(f);
  u += 0x7fffu + ((u >> 16) & 1u);   // RNE
  return (u16)(u >> 16);
}
__device__ __forceinline__ float bf2f(u16 h) {
  return __uint_as_float(((unsigned int)h) << 16);
}

// --------------------------- weight transpose+cast -------------------------
// W [K=1024][N=1024] f32 -> WT [N][K] bf16.  grid 256 blocks x 256 thr.
__global__ __launch_bounds__(256) void cvt_w_kern(const float* __restrict__ W,
                                                  u16* __restrict__ WT) {
  __shared__ float tile[64][65];
  const int blk = blockIdx.x;
  const int k0 = (blk >> 4) << 6;
  const int n0 = (blk & 15) << 6;
  const int tid = threadIdx.x;
  const int r = tid >> 6;
  const int c = tid & 63;
#pragma unroll
  for (int i = 0; i < 16; ++i) {
    int row = (i << 2) + r;
    tile[row][c] = W[(size_t)(k0 + row) * DIMN + n0 + c];
  }
  __syncthreads();
#pragma unroll
  for (int i = 0; i < 16; ++i) {
    int row = (i << 2) + r;  // n offset
    WT[(size_t)(n0 + row) * DIMN + k0 + c] = f2bf(tile[c][row]);
  }
}

// --------------------------- x cast ----------------------------------------
__global__ __launch_bounds__(256) void cvt_x_kern(const float* __restrict__ x,
                                                  u16* __restrict__ xb) {
  size_t i = ((size_t)blockIdx.x * 256 + threadIdx.x) * 4;
  f32x4 v = *(const f32x4*)(x + i);
  s16x4 o;
  o.x = (short)f2bf(v.x); o.y = (short)f2bf(v.y);
  o.z = (short)f2bf(v.z); o.w = (short)f2bf(v.w);
  *(s16x4*)(xb + i) = o;
}

// --------------------------- bf16 MFMA GEMM (m97 structure) -----------------
// C[M=16384][N=1024] = A[M][K=1024] * Bt[N][K]^T ; MODE: 1=elu+1->bf16,
// 2=copy->bf16, 3=+bias->f32.  128x128 tile, BK=32, 4 waves (2x2 of 64x64).
template <int MODE>
__global__ __launch_bounds__(256) void gemm_bt(const u16* __restrict__ A,
                                               const u16* __restrict__ Bt,
                                               void* __restrict__ Cout,
                                               const float* __restrict__ bias) {
  constexpr int N = DIMN, K = DIMN;
  __shared__ u16 As[128 * 32];
  __shared__ u16 Bs[128 * 32];
  const int tid = threadIdx.x;
  const int l = tid & 63;
  const int w = tid >> 6;
  const int wm = (w >> 1) << 6;
  const int wn = (w & 1) << 6;
  const int bm = (int)blockIdx.x >> 3;   // N/128 = 8 tiles
  const int bn = (int)blockIdx.x & 7;
  const size_t arow0 = (size_t)bm * 128;
  const size_t brow0 = (size_t)bn * 128;
  const int lrow = l >> 2;
  const int lcol = (l & 3) << 3;   // ushort offset (16B per lane)

  f32x4 acc[4][4];
#pragma unroll
  for (int i = 0; i < 4; ++i)
#pragma unroll
    for (int j = 0; j < 4; ++j) acc[i][j] = {0.f, 0.f, 0.f, 0.f};

  for (int kt = 0; kt < K; kt += 32) {
    // stage A(8KB)+B(8KB): 16 chunks of 16 rows x 32 cols; wave w -> chunks 4w..4w+3
#pragma unroll
    for (int i = 0; i < 4; ++i) {
      const int c = (w << 2) + i;
      const int ca = c & 7;
      const u16* gsrc = (c < 8)
          ? A  + (arow0 + (size_t)(ca * 16 + lrow)) * K + kt + lcol
          : Bt + (brow0 + (size_t)(ca * 16 + lrow)) * K + kt + lcol;
      u16* ldst = (c < 8) ? &As[ca * 512] : &Bs[ca * 512];
      __builtin_amdgcn_global_load_lds(
          (__attribute__((address_space(1))) const void*)gsrc,
          (__attribute__((address_space(3))) void*)ldst, 16, 0, 0);
    }
    __syncthreads();
    const int fr = l & 15;
    const int kg = (l >> 4) << 3;
    s16x8 af[4], bf[4];
#pragma unroll
    for (int mi = 0; mi < 4; ++mi)
      af[mi] = *(const s16x8*)&As[(wm + mi * 16 + fr) * 32 + kg];
#pragma unroll
    for (int ni = 0; ni < 4; ++ni)
      bf[ni] = *(const s16x8*)&Bs[(wn + ni * 16 + fr) * 32 + kg];
#pragma unroll
    for (int mi = 0; mi < 4; ++mi)
#pragma unroll
      for (int ni = 0; ni < 4; ++ni)
        acc[mi][ni] = __builtin_amdgcn_mfma_f32_16x16x32_bf16(
            af[mi], bf[ni], acc[mi][ni], 0, 0, 0);
    __syncthreads();
  }
  // epilogue: D[row][col], col = lane&15, row = (lane>>4)*4 + j
  const int r0 = (l >> 4) << 2;
  const int c0 = l & 15;
#pragma unroll
  for (int mi = 0; mi < 4; ++mi) {
#pragma unroll
    for (int ni = 0; ni < 4; ++ni) {
      const size_t col = brow0 + wn + ni * 16 + c0;
#pragma unroll
      for (int j = 0; j < 4; ++j) {
        const size_t row = arow0 + wm + mi * 16 + r0 + j;
        float v = acc[mi][ni][j];
        if constexpr (MODE == 1) {        // elu+1 -> bf16
          float r = v > 0.f ? v + 1.f : __expf(v);
          ((u16*)Cout)[row * N + col] = f2bf(r);
        } else if constexpr (MODE == 2) { // copy -> bf16
          ((u16*)Cout)[row * N + col] = f2bf(v);
        } else {                          // +bias -> f32
          ((float*)Cout)[row * N + col] = v + bias[col];
        }
      }
    }
  }
}

// --------------------------- per-head softmax over 64, in-place -------------
__global__ __launch_bounds__(256) void softmax64_kern(u16* __restrict__ qb) {
  const size_t gid = (size_t)blockIdx.x * 256 + threadIdx.x;
  const int l = (int)(gid & 63);
  const size_t wid = gid >> 6;           // row-head id
  const size_t row = wid >> 4;
  const int h = (int)(wid & 15);
  const size_t idx = row * DIMN + (size_t)h * 64 + l;
  float v = bf2f(qb[idx]);
  float m = v;
#pragma unroll
  for (int off = 32; off > 0; off >>= 1) m = fmaxf(m, __shfl_xor(m, off));
  float e = __expf(v - m);
  float s = e;
#pragma unroll
  for (int off = 32; off > 0; off >>= 1) s += __shfl_xor(s, off);
  qb[idx] = f2bf(e / s);
}

// --------------------------- per-bucket context: C_u = k_u^T v_u ------------
// grid 4096 = (b*16+h)*64+u blocks.  ctx layout [bh][u][d][e] f32, ksum [bh][u][d].
__global__ __launch_bounds__(256) void ctx_bucket_kern(const u16* __restrict__ kb,
                                                       const u16* __restrict__ vb,
                                                       float* __restrict__ ctx,
                                                       float* __restrict__ ksum) {
  __shared__ float kl[4096];
  __shared__ float vl[4096];
  const int blk = blockIdx.x;
  const int u = blk & 63;
  const int bh = blk >> 6;
  const int b = bh >> 4, h = bh & 15;
  const size_t rowbase = (size_t)b * T_LEN + (size_t)u * 64;
  const int tid = threadIdx.x;
#pragma unroll
  for (int i = 0; i < 16; ++i) {
    int idx = i * 256 + tid;
    int n = idx >> 6, d = idx & 63;
    size_t g = (rowbase + n) * DIMN + (size_t)h * 64 + d;
    kl[idx] = bf2f(kb[g]);
    vl[idx] = bf2f(vb[g]);
  }
  __syncthreads();
  const int dq = (tid & 15) << 2;
  const int eq = (tid >> 4) << 2;
  float a[4][4] = {};
  float ks[4] = {};
  for (int n = 0; n < 64; ++n) {
    f32x4 kv = *(const f32x4*)&kl[n * 64 + dq];
    f32x4 vv = *(const f32x4*)&vl[n * 64 + eq];
#pragma unroll
    for (int i = 0; i < 4; ++i) {
      ks[i] += kv[i];
#pragma unroll
      for (int j = 0; j < 4; ++j) a[i][j] += kv[i] * vv[j];
    }
  }
  const size_t cbase = (size_t)blk * 4096;
#pragma unroll
  for (int i = 0; i < 4; ++i) {
    f32x4 o = {a[i][0], a[i][1], a[i][2], a[i][3]};
    *(f32x4*)&ctx[cbase + (size_t)(dq + i) * 64 + eq] = o;
  }
  if ((tid >> 4) == 0) {
    f32x4 o = {ks[0], ks[1], ks[2], ks[3]};
    *(f32x4*)&ksum[(size_t)blk * 64 + dq] = o;
  }
}

// --------------------------- cumsum over u + normalize + shift, in place ----
// thread owns (bh, d, e-quad); 65536 threads.
__global__ __launch_bounds__(256) void ctx_cumnorm_kern(float* __restrict__ ctx,
                                                        const float* __restrict__ ksum) {
  const int tid = blockIdx.x * 256 + threadIdx.x;
  const int bh = tid >> 10;
  const int rem = tid & 1023;
  const int d = rem >> 4;
  const int e0 = (rem & 15) << 2;
  float c0 = 0.f, c1 = 0.f, c2 = 0.f, c3 = 0.f, accK = 0.f;
  for (int u = 0; u < 64; ++u) {
    const size_t base = ((size_t)(bh * 64 + u)) * 4096 + (size_t)d * 64 + e0;
    f32x4 c = *(const f32x4*)&ctx[base];
    float kk = ksum[(size_t)(bh * 64 + u) * 64 + d];
    f32x4 o;
    if (u == 0) {
      o = {0.f, 0.f, 0.f, 0.f};
    } else {
      float inv = 1.f / (accK + 1e-6f);
      o = {c0 * inv, c1 * inv, c2 * inv, c3 * inv};
    }
    *(f32x4*)&ctx[base] = o;                       // bucket u sees <= u-1
    c0 += c.x; c1 += c.y; c2 += c.z; c3 += c.w;
    accK += kk;
  }
}

// --------------------------- per-bucket attn: q_u @ ctx_u -------------------
__global__ __launch_bounds__(256) void attn_bucket_kern(const u16* __restrict__ qb,
                                                        const float* __restrict__ ctx,
                                                        u16* __restrict__ attn) {
  __shared__ float qT[64 * 68];   // transposed [d][n], padded
  __shared__ float cl[4096];      // [d][e]
  const int blk = blockIdx.x;
  const int u = blk & 63;
  const int bh = blk >> 6;
  const int b = bh >> 4, h = bh & 15;
  const size_t rowbase = (size_t)b * T_LEN + (size_t)u * 64;
  const int tid = threadIdx.x;
  const size_t cbase = (size_t)blk * 4096;
#pragma unroll
  for (int i = 0; i < 16; ++i) {
    int idx = i * 256 + tid;
    int n = idx >> 6, d = idx & 63;
    qT[d * 68 + n] = bf2f(qb[(rowbase + n) * DIMN + (size_t)h * 64 + d]);
    cl[idx] = ctx[cbase + idx];
  }
  __syncthreads();
  const int nq = (tid & 15) << 2;
  const int eq = (tid >> 4) << 2;
  float a[4][4] = {};
  for (int d = 0; d < 64; ++d) {
    f32x4 qv = *(const f32x4*)&qT[d * 68 + nq];
    f32x4 cv = *(const f32x4*)&cl[d * 64 + eq];
#pragma unroll
    for (int i = 0; i < 4; ++i)
#pragma unroll
      for (int j = 0; j < 4; ++j) a[i][j] += qv[i] * cv[j];
  }
#pragma unroll
  for (int i = 0; i < 4; ++i) {
    s16x4 o;
    o.x = (short)f2bf(a[i][0]); o.y = (short)f2bf(a[i][1]);
    o.z = (short)f2bf(a[i][2]); o.w = (short)f2bf(a[i][3]);
    *(s16x4*)&attn[(rowbase + nq + i) * DIMN + (size_t)h * 64 + eq] = o;
  }
}

// ---------------------------------------------------------------------------
extern "C" void kernel_launch(void* const* d_in, const int* in_sizes, int n_in,
                              void* d_out, int out_size, void* d_ws, size_t ws_size,
                              hipStream_t stream) {
  const float* x  = (const float*)d_in[0];
  const float* Wq = (const float*)d_in[1];
  const float* Wk = (const float*)d_in[2];
  const float* Wv = (const float*)d_in[3];
  const float* Wo = (const float*)d_in[4];
  const float* bo = (const float*)d_in[5];
  float* out = (float*)d_out;

  // workspace layout (bytes); total ~210.8 MB
  constexpr size_t SZ_XB = (size_t)MROWS * DIMN * 2;   // 33,554,432
  constexpr size_t SZ_WT = (size_t)DIMN * DIMN * 2;    //  2,097,152
  constexpr size_t SZ_CTX = (size_t)NB * NHEAD * 64 * 64 * 64 * 4; // 67,108,864
  char* ws = (char*)d_ws;
  u16*   xb   = (u16*)(ws);
  u16*   wqT  = (u16*)(ws + SZ_XB);
  u16*   wkT  = (u16*)(ws + SZ_XB + SZ_WT);
  u16*   wvT  = (u16*)(ws + SZ_XB + 2 * SZ_WT);
  u16*   woT  = (u16*)(ws + SZ_XB + 3 * SZ_WT);
  u16*   qb   = (u16*)(ws + SZ_XB + 4 * SZ_WT);
  u16*   kb   = (u16*)(ws + 2 * SZ_XB + 4 * SZ_WT);
  u16*   vb   = (u16*)(ws + 3 * SZ_XB + 4 * SZ_WT);
  float* ctx  = (float*)(ws + 4 * SZ_XB + 4 * SZ_WT);
  float* ksum = (float*)(ws + 4 * SZ_XB + 4 * SZ_WT + SZ_CTX);
  u16*   attn = xb;  // xb is dead after the 3 input GEMMs

  cvt_w_kern<<<256, 256, 0, stream>>>(Wq, wqT);
  cvt_w_kern<<<256, 256, 0, stream>>>(Wk, wkT);
  cvt_w_kern<<<256, 256, 0, stream>>>(Wv, wvT);
  cvt_w_kern<<<256, 256, 0, stream>>>(Wo, woT);
  cvt_x_kern<<<MROWS * DIMN / 4 / 256, 256, 0, stream>>>(x, xb);

  gemm_bt<2><<<1024, 256, 0, stream>>>(xb, wqT, (void*)qb, nullptr);  // q
  gemm_bt<1><<<1024, 256, 0, stream>>>(xb, wkT, (void*)kb, nullptr);  // k=elu+1
  gemm_bt<2><<<1024, 256, 0, stream>>>(xb, wvT, (void*)vb, nullptr);  // v

  softmax64_kern<<<MROWS * NHEAD / 4, 256, 0, stream>>>(qb);
  ctx_bucket_kern<<<NB * NHEAD * 64, 256, 0, stream>>>(kb, vb, ctx, ksum);
  ctx_cumnorm_kern<<<256, 256, 0, stream>>>(ctx, ksum);
  attn_bucket_kern<<<NB * NHEAD * 64, 256, 0, stream>>>(qb, ctx, attn);

  gemm_bt<3><<<1024, 256, 0, stream>>>(attn, woT, (void*)out, bo);
}

// Round 3
// 287.131 us; speedup vs baseline: 1.4421x; 1.4421x over previous
//
#include <hip/hip_runtime.h>

// ---------------------------------------------------------------------------
// LinearSelfAttention: B=4 T=4096 DIM=1024 H=16 E=64 BUCKET=64 U=64
// ---------------------------------------------------------------------------

#define T_LEN 4096
#define DIMN  1024
#define NHEAD 16
#define NB    4
#define MROWS (NB * T_LEN)   // 16384

typedef float f32x4 __attribute__((ext_vector_type(4)));
typedef short s16x8 __attribute__((ext_vector_type(8)));
typedef short s16x4 __attribute__((ext_vector_type(4)));
using u16 = unsigned short;

__device__ __forceinline__ u16 f2bf(float f) {
  unsigned int u = __float_as_uint(f);
  u += 0x7fffu + ((u >> 16) & 1u);   // RNE
  return (u16)(u >> 16);
}
__device__ __forceinline__ float bf2f(u16 h) {
  return __uint_as_float(((unsigned int)h) << 16);
}
// involution swizzle within a 16KB half-slot ([256 rows][32 bf16] = row*64B)
__device__ __forceinline__ int swz16k(int off) {
  return off ^ (((off >> 7) & 3) << 4);
}

// --------------------------- weight transpose+cast -------------------------
__global__ __launch_bounds__(256) void cvt_w_kern(const float* __restrict__ W,
                                                  u16* __restrict__ WT) {
  __shared__ float tile[64][65];
  const int blk = blockIdx.x;
  const int k0 = (blk >> 4) << 6;
  const int n0 = (blk & 15) << 6;
  const int tid = threadIdx.x;
  const int r = tid >> 6;
  const int c = tid & 63;
#pragma unroll
  for (int i = 0; i < 16; ++i) {
    int row = (i << 2) + r;
    tile[row][c] = W[(size_t)(k0 + row) * DIMN + n0 + c];
  }
  __syncthreads();
#pragma unroll
  for (int i = 0; i < 16; ++i) {
    int row = (i << 2) + r;
    WT[(size_t)(n0 + row) * DIMN + k0 + c] = f2bf(tile[c][row]);
  }
}

// --------------------------- x cast ----------------------------------------
__global__ __launch_bounds__(256) void cvt_x_kern(const float* __restrict__ x,
                                                  u16* __restrict__ xb) {
  size_t i = ((size_t)blockIdx.x * 256 + threadIdx.x) * 4;
  f32x4 v = *(const f32x4*)(x + i);
  s16x4 o;
  o.x = (short)f2bf(v.x); o.y = (short)f2bf(v.y);
  o.z = (short)f2bf(v.z); o.w = (short)f2bf(v.w);
  *(s16x4*)(xb + i) = o;
}

// --------------------------- 256x256 8-phase bf16 GEMM ----------------------
// C[M][N] = A[M][1024] * Bt[N][1024]^T.
// MODE 0: N=3072 fused QKV -> q (softmax64, bf16), k (elu+1, bf16), v (bf16)
// MODE 1: N=1024 -> f32 out + bias
// 512 threads = 8 waves (2Mx4N); per-wave 128x64; BK=64 (two 32-K-halves).
// LDS 128KB dynamic: 2 buffers x [A-K0|A-K1|B-K0|B-K1] x 16KB.
// Sync protocol: counted vmcnt(8) ONLY at end of ph2/ph4, immediately before
// the closing barrier -> every dependent ds_read sits after a barrier that
// follows every wave's covering vmcnt (fixes R2's cross-wave LDS race).
template <int MODE>
__global__ __launch_bounds__(512, 2) void gemm256(
    const u16* __restrict__ A, const u16* __restrict__ Bt,
    u16* __restrict__ dq, u16* __restrict__ dk, u16* __restrict__ dv,
    float* __restrict__ dO, const float* __restrict__ bias) {
  constexpr int K = 1024;
  constexpr int BNT = (MODE == 0) ? 12 : 4;   // N / 256
  constexpr int NT = K / 64;                  // 16 K-tiles
  extern __shared__ char lds[];

  const int tid = threadIdx.x;
  const int l = tid & 63;
  const int w = tid >> 6;
  const int wm = w >> 2;           // 0..1
  const int wn = w & 3;            // 0..3

  // XCD-bijective swizzle (gridDim.x % 8 == 0 for both grids)
  const int nwg = (int)gridDim.x;
  const int bid = (int)blockIdx.x;
  const int swz = (bid & 7) * (nwg >> 3) + (bid >> 3);
  const int bm = swz / BNT, bn = swz % BNT;
  const size_t arow0 = (size_t)bm * 256;
  const size_t brow0 = (size_t)bn * 256;

  // staging decode: thread writes phys off tid*16 (+ issue*8192) in a half-slot;
  // logical element there = swz16k(phys)
  int lrow[2], lcol[2];
#pragma unroll
  for (int i = 0; i < 2; ++i) {
    int lg = swz16k(tid * 16 + i * 8192);
    lrow[i] = lg >> 6;
    lcol[i] = (lg & 63) >> 1;
  }

  // read-side swizzle collapses to a per-lane XOR on the k-column slot
  const int fr = l & 15;
  const int kswz = (((l >> 4) << 4)) ^ ((((fr >> 1) & 3)) << 4);

  auto STAGE = [&](int matsel, int kh, int tt) {   // matsel 0=A 1=B
    const int kbase = (tt & (NT - 1)) * 64 + kh * 32;   // wrap tail (harmless)
#pragma unroll
    for (int i = 0; i < 2; ++i) {
      const u16* src = (matsel == 0)
          ? A  + (arow0 + (size_t)lrow[i]) * K + kbase + lcol[i]
          : Bt + (brow0 + (size_t)lrow[i]) * K + kbase + lcol[i];
      char* dst = lds + ((tt & 1) * 65536 + (matsel * 2 + kh) * 16384 +
                         i * 8192 + w * 1024);
      __builtin_amdgcn_global_load_lds(
          (__attribute__((address_space(1))) const void*)src,
          (__attribute__((address_space(3))) void*)dst, 16, 0, 0);
    }
  };
  auto LDA = [&](int buf, int kh, int rowb) -> s16x8 {
    return *(const s16x8*)(lds + buf * 65536 + kh * 16384 + rowb * 64 + kswz);
  };
  auto LDB = [&](int buf, int kh, int rowb) -> s16x8 {
    return *(const s16x8*)(lds + buf * 65536 + 32768 + kh * 16384 + rowb * 64 + kswz);
  };

  f32x4 acc[8][4];
#pragma unroll
  for (int i = 0; i < 8; ++i)
#pragma unroll
    for (int j = 0; j < 4; ++j) acc[i][j] = {0.f, 0.f, 0.f, 0.f};

  // prologue: tile0 full, tile1 K0; drain tile0-K0 (12 outstanding -> 8)
  STAGE(0, 0, 0); STAGE(1, 0, 0); STAGE(0, 1, 0); STAGE(1, 1, 0);
  STAGE(0, 0, 1); STAGE(1, 0, 1);
  asm volatile("s_waitcnt vmcnt(8)" ::: "memory");
  __builtin_amdgcn_sched_barrier(0);
  __builtin_amdgcn_s_barrier();

  const int amb = wm * 128;
  const int bnb = wn * 64;
  s16x8 af[4], bfr[4];

  for (int t = 0; t < NT; ++t) {
    const int buf = t & 1;
    // ---- phase 1: kh0, mi 0-3 x ni 0-3; stage A-K1(t+1) --------------------
#pragma unroll
    for (int i = 0; i < 4; ++i) af[i]  = LDA(buf, 0, amb + i * 16 + fr);
#pragma unroll
    for (int i = 0; i < 4; ++i) bfr[i] = LDB(buf, 0, bnb + i * 16 + fr);
    STAGE(0, 1, t + 1);
    __builtin_amdgcn_s_barrier();
    asm volatile("s_waitcnt lgkmcnt(0)" ::: "memory");
    __builtin_amdgcn_sched_barrier(0);
    __builtin_amdgcn_s_setprio(1);
#pragma unroll
    for (int mi = 0; mi < 4; ++mi)
#pragma unroll
      for (int ni = 0; ni < 4; ++ni)
        acc[mi][ni] = __builtin_amdgcn_mfma_f32_16x16x32_bf16(
            af[mi], bfr[ni], acc[mi][ni], 0, 0, 0);
    __builtin_amdgcn_s_setprio(0);
    __builtin_amdgcn_s_barrier();
    // ---- phase 2: kh0, mi 4-7 (reuse B); stage B-K1(t+1); drain K1(t) ------
#pragma unroll
    for (int i = 0; i < 4; ++i) af[i] = LDA(buf, 0, amb + (4 + i) * 16 + fr);
    STAGE(1, 1, t + 1);
    __builtin_amdgcn_s_barrier();
    asm volatile("s_waitcnt lgkmcnt(0)" ::: "memory");
    __builtin_amdgcn_sched_barrier(0);
    __builtin_amdgcn_s_setprio(1);
#pragma unroll
    for (int mi = 0; mi < 4; ++mi)
#pragma unroll
      for (int ni = 0; ni < 4; ++ni)
        acc[4 + mi][ni] = __builtin_amdgcn_mfma_f32_16x16x32_bf16(
            af[mi], bfr[ni], acc[4 + mi][ni], 0, 0, 0);
    __builtin_amdgcn_s_setprio(0);
    asm volatile("s_waitcnt vmcnt(8)" ::: "memory");   // K1(t) landed, all waves
    __builtin_amdgcn_sched_barrier(0);
    __builtin_amdgcn_s_barrier();
    // ---- phase 3: kh1, mi 0-3 x ni 0-3; stage A-K0(t+2) --------------------
#pragma unroll
    for (int i = 0; i < 4; ++i) af[i]  = LDA(buf, 1, amb + i * 16 + fr);
#pragma unroll
    for (int i = 0; i < 4; ++i) bfr[i] = LDB(buf, 1, bnb + i * 16 + fr);
    STAGE(0, 0, t + 2);
    __builtin_amdgcn_s_barrier();
    asm volatile("s_waitcnt lgkmcnt(0)" ::: "memory");
    __builtin_amdgcn_sched_barrier(0);
    __builtin_amdgcn_s_setprio(1);
#pragma unroll
    for (int mi = 0; mi < 4; ++mi)
#pragma unroll
      for (int ni = 0; ni < 4; ++ni)
        acc[mi][ni] = __builtin_amdgcn_mfma_f32_16x16x32_bf16(
            af[mi], bfr[ni], acc[mi][ni], 0, 0, 0);
    __builtin_amdgcn_s_setprio(0);
    __builtin_amdgcn_s_barrier();
    // ---- phase 4: kh1, mi 4-7 (reuse B); stage B-K0(t+2); drain K0(t+1) ----
#pragma unroll
    for (int i = 0; i < 4; ++i) af[i] = LDA(buf, 1, amb + (4 + i) * 16 + fr);
    STAGE(1, 0, t + 2);
    __builtin_amdgcn_s_barrier();
    asm volatile("s_waitcnt lgkmcnt(0)" ::: "memory");
    __builtin_amdgcn_sched_barrier(0);
    __builtin_amdgcn_s_setprio(1);
#pragma unroll
    for (int mi = 0; mi < 4; ++mi)
#pragma unroll
      for (int ni = 0; ni < 4; ++ni)
        acc[4 + mi][ni] = __builtin_amdgcn_mfma_f32_16x16x32_bf16(
            af[mi], bfr[ni], acc[4 + mi][ni], 0, 0, 0);
    __builtin_amdgcn_s_setprio(0);
    asm volatile("s_waitcnt vmcnt(8)" ::: "memory");   // K0(t+1) landed, all waves
    __builtin_amdgcn_sched_barrier(0);
    __builtin_amdgcn_s_barrier();
  }

  // ---------------- epilogue: C row = (lane>>4)*4+j, col = lane&15 ----------
  const int r0 = (l >> 4) << 2;
  const int c0 = l & 15;
  if constexpr (MODE == 0) {
    const int mat = bn >> 2;                        // 0=q 1=k 2=v
    u16* dst = (mat == 0) ? dq : ((mat == 1) ? dk : dv);
    const size_t colbase = (size_t)(bn & 3) * 256 + (size_t)wn * 64;
    if (mat == 0) {
      // fused per-head softmax over the wave's 64 cols (= one head)
#pragma unroll
      for (int mi = 0; mi < 8; ++mi) {
#pragma unroll
        for (int j = 0; j < 4; ++j) {
          float v0 = acc[mi][0][j], v1 = acc[mi][1][j];
          float v2 = acc[mi][2][j], v3 = acc[mi][3][j];
          float m = fmaxf(fmaxf(v0, v1), fmaxf(v2, v3));
#pragma unroll
          for (int off = 1; off < 16; off <<= 1) m = fmaxf(m, __shfl_xor(m, off));
          float e0 = __expf(v0 - m), e1 = __expf(v1 - m);
          float e2 = __expf(v2 - m), e3 = __expf(v3 - m);
          float s = e0 + e1 + e2 + e3;
#pragma unroll
          for (int off = 1; off < 16; off <<= 1) s += __shfl_xor(s, off);
          float inv = 1.f / s;
          const size_t row = arow0 + wm * 128 + mi * 16 + r0 + j;
          u16* p = dst + row * DIMN + colbase + c0;
          p[0]  = f2bf(e0 * inv); p[16] = f2bf(e1 * inv);
          p[32] = f2bf(e2 * inv); p[48] = f2bf(e3 * inv);
        }
      }
    } else {
#pragma unroll
      for (int mi = 0; mi < 8; ++mi)
#pragma unroll
        for (int ni = 0; ni < 4; ++ni)
#pragma unroll
          for (int j = 0; j < 4; ++j) {
            const size_t row = arow0 + wm * 128 + mi * 16 + r0 + j;
            float v = acc[mi][ni][j];
            float r = (mat == 1) ? (v > 0.f ? v + 1.f : __expf(v)) : v;
            dst[row * DIMN + colbase + ni * 16 + c0] = f2bf(r);
          }
    }
  } else {
    const size_t colbase = brow0 + (size_t)wn * 64;
#pragma unroll
    for (int mi = 0; mi < 8; ++mi)
#pragma unroll
      for (int ni = 0; ni < 4; ++ni) {
        const size_t col = colbase + ni * 16 + c0;
        const float bv = bias[col];
#pragma unroll
        for (int j = 0; j < 4; ++j) {
          const size_t row = arow0 + wm * 128 + mi * 16 + r0 + j;
          dO[row * DIMN + col] = acc[mi][ni][j] + bv;
        }
      }
  }
}

// --------------------------- per-bucket context: C_u = k_u^T v_u ------------
__global__ __launch_bounds__(256) void ctx_bucket_kern(const u16* __restrict__ kb,
                                                       const u16* __restrict__ vb,
                                                       float* __restrict__ ctx,
                                                       float* __restrict__ ksum) {
  __shared__ float kl[4096];
  __shared__ float vl[4096];
  const int blk = blockIdx.x;
  const int u = blk & 63;
  const int bh = blk >> 6;
  const int b = bh >> 4, h = bh & 15;
  const size_t rowbase = (size_t)b * T_LEN + (size_t)u * 64;
  const int tid = threadIdx.x;
#pragma unroll
  for (int i = 0; i < 16; ++i) {
    int idx = i * 256 + tid;
    int n = idx >> 6, d = idx & 63;
    size_t g = (rowbase + n) * DIMN + (size_t)h * 64 + d;
    kl[idx] = bf2f(kb[g]);
    vl[idx] = bf2f(vb[g]);
  }
  __syncthreads();
  const int dq = (tid & 15) << 2;
  const int eq = (tid >> 4) << 2;
  float a[4][4] = {};
  float ks[4] = {};
  for (int n = 0; n < 64; ++n) {
    f32x4 kv = *(const f32x4*)&kl[n * 64 + dq];
    f32x4 vv = *(const f32x4*)&vl[n * 64 + eq];
#pragma unroll
    for (int i = 0; i < 4; ++i) {
      ks[i] += kv[i];
#pragma unroll
      for (int j = 0; j < 4; ++j) a[i][j] += kv[i] * vv[j];
    }
  }
  const size_t cbase = (size_t)blk * 4096;
#pragma unroll
  for (int i = 0; i < 4; ++i) {
    f32x4 o = {a[i][0], a[i][1], a[i][2], a[i][3]};
    *(f32x4*)&ctx[cbase + (size_t)(dq + i) * 64 + eq] = o;
  }
  if ((tid >> 4) == 0) {
    f32x4 o = {ks[0], ks[1], ks[2], ks[3]};
    *(f32x4*)&ksum[(size_t)blk * 64 + dq] = o;
  }
}

// --------------------------- cumsum over u + normalize + shift, in place ----
__global__ __launch_bounds__(256) void ctx_cumnorm_kern(float* __restrict__ ctx,
                                                        const float* __restrict__ ksum) {
  const int tid = blockIdx.x * 256 + threadIdx.x;   // 262144 chains
  const int bh = tid >> 12;
  const int rem = tid & 4095;
  const int d = rem >> 6;
  const int e = rem & 63;
  float c = 0.f, accK = 0.f;
  for (int u = 0; u < 64; ++u) {
    const size_t base = ((size_t)(bh * 64 + u)) * 4096 + (size_t)d * 64 + e;
    float cv = ctx[base];
    float kk = ksum[(size_t)(bh * 64 + u) * 64 + d];
    float o = (u == 0) ? 0.f : c / (accK + 1e-6f);
    ctx[base] = o;
    c += cv; accK += kk;
  }
}

// --------------------------- per-bucket attn: q_u @ ctx_u -------------------
__global__ __launch_bounds__(256) void attn_bucket_kern(const u16* __restrict__ qb,
                                                        const float* __restrict__ ctx,
                                                        u16* __restrict__ attn) {
  __shared__ float qT[64 * 68];
  __shared__ float cl[4096];
  const int blk = blockIdx.x;
  const int u = blk & 63;
  const int bh = blk >> 6;
  const int b = bh >> 4, h = bh & 15;
  const size_t rowbase = (size_t)b * T_LEN + (size_t)u * 64;
  const int tid = threadIdx.x;
  const size_t cbase = (size_t)blk * 4096;
#pragma unroll
  for (int i = 0; i < 16; ++i) {
    int idx = i * 256 + tid;
    int n = idx >> 6, d = idx & 63;
    qT[d * 68 + n] = bf2f(qb[(rowbase + n) * DIMN + (size_t)h * 64 + d]);
    cl[idx] = ctx[cbase + idx];
  }
  __syncthreads();
  const int nq = (tid & 15) << 2;
  const int eq = (tid >> 4) << 2;
  float a[4][4] = {};
  for (int d = 0; d < 64; ++d) {
    f32x4 qv = *(const f32x4*)&qT[d * 68 + nq];
    f32x4 cv = *(const f32x4*)&cl[d * 64 + eq];
#pragma unroll
    for (int i = 0; i < 4; ++i)
#pragma unroll
      for (int j = 0; j < 4; ++j) a[i][j] += qv[i] * cv[j];
  }
#pragma unroll
  for (int i = 0; i < 4; ++i) {
    s16x4 o;
    o.x = (short)f2bf(a[i][0]); o.y = (short)f2bf(a[i][1]);
    o.z = (short)f2bf(a[i][2]); o.w = (short)f2bf(a[i][3]);
    *(s16x4*)&attn[(rowbase + nq + i) * DIMN + (size_t)h * 64 + eq] = o;
  }
}

// ---------------------------------------------------------------------------
extern "C" void kernel_launch(void* const* d_in, const int* in_sizes, int n_in,
                              void* d_out, int out_size, void* d_ws, size_t ws_size,
                              hipStream_t stream) {
  const float* x  = (const float*)d_in[0];
  const float* Wq = (const float*)d_in[1];
  const float* Wk = (const float*)d_in[2];
  const float* Wv = (const float*)d_in[3];
  const float* Wo = (const float*)d_in[4];
  const float* bo = (const float*)d_in[5];
  float* out = (float*)d_out;

  constexpr size_t SZ_XB = (size_t)MROWS * DIMN * 2;
  constexpr size_t SZ_WT = (size_t)DIMN * DIMN * 2;
  constexpr size_t SZ_CTX = (size_t)NB * NHEAD * 64 * 64 * 64 * 4;
  char* ws = (char*)d_ws;
  u16*   xb   = (u16*)(ws);
  u16*   wqT  = (u16*)(ws + SZ_XB);          // wq/wk/wv contiguous = [3072][1024]
  u16*   wkT  = (u16*)(ws + SZ_XB + SZ_WT);
  u16*   wvT  = (u16*)(ws + SZ_XB + 2 * SZ_WT);
  u16*   woT  = (u16*)(ws + SZ_XB + 3 * SZ_WT);
  u16*   qb   = (u16*)(ws + SZ_XB + 4 * SZ_WT);
  u16*   kb   = (u16*)(ws + 2 * SZ_XB + 4 * SZ_WT);
  u16*   vb   = (u16*)(ws + 3 * SZ_XB + 4 * SZ_WT);
  float* ctx  = (float*)(ws + 4 * SZ_XB + 4 * SZ_WT);
  float* ksum = (float*)(ws + 4 * SZ_XB + 4 * SZ_WT + SZ_CTX);
  u16*   attn = xb;  // xb dead after QKV GEMM

  (void)hipFuncSetAttribute((const void*)gemm256<0>,
                            hipFuncAttributeMaxDynamicSharedMemorySize, 131072);
  (void)hipFuncSetAttribute((const void*)gemm256<1>,
                            hipFuncAttributeMaxDynamicSharedMemorySize, 131072);

  cvt_w_kern<<<256, 256, 0, stream>>>(Wq, wqT);
  cvt_w_kern<<<256, 256, 0, stream>>>(Wk, wkT);
  cvt_w_kern<<<256, 256, 0, stream>>>(Wv, wvT);
  cvt_w_kern<<<256, 256, 0, stream>>>(Wo, woT);
  cvt_x_kern<<<MROWS * DIMN / 4 / 256, 256, 0, stream>>>(x, xb);

  // fused QKV: N = 3072, grid 64 x 12 = 768
  gemm256<0><<<768, 512, 131072, stream>>>(xb, wqT, qb, kb, vb, nullptr, nullptr);

  ctx_bucket_kern<<<NB * NHEAD * 64, 256, 0, stream>>>(kb, vb, ctx, ksum);
  ctx_cumnorm_kern<<<1024, 256, 0, stream>>>(ctx, ksum);
  attn_bucket_kern<<<NB * NHEAD * 64, 256, 0, stream>>>(qb, ctx, attn);

  // output: N = 1024, grid 64 x 4 = 256
  gemm256<1><<<256, 512, 131072, stream>>>(attn, woT, nullptr, nullptr, nullptr, out, bo);
}

// Round 4
// 284.370 us; speedup vs baseline: 1.4561x; 1.0097x over previous
//
#include <hip/hip_runtime.h>

// ---------------------------------------------------------------------------
// LinearSelfAttention: B=4 T=4096 DIM=1024 H=16 E=64 BUCKET=64 U=64
// ---------------------------------------------------------------------------

#define T_LEN 4096
#define DIMN  1024
#define NHEAD 16
#define NB    4
#define MROWS (NB * T_LEN)   // 16384

typedef float f32x4 __attribute__((ext_vector_type(4)));
typedef short s16x8 __attribute__((ext_vector_type(8)));
typedef short s16x4 __attribute__((ext_vector_type(4)));
using u16 = unsigned short;

__device__ __forceinline__ u16 f2bf(float f) {
  unsigned int u = __float_as_uint(f);
  u += 0x7fffu + ((u >> 16) & 1u);   // RNE
  return (u16)(u >> 16);
}
__device__ __forceinline__ float bf2f(u16 h) {
  return __uint_as_float(((unsigned int)h) << 16);
}
// involution swizzle within a 16KB half-slot ([256 rows][32 bf16] = row*64B)
__device__ __forceinline__ int swz16k(int off) {
  return off ^ (((off >> 7) & 3) << 4);
}

// --------------------------- weight transpose+cast (all 4 in one launch) ----
__global__ __launch_bounds__(256) void cvt_w_kern(const float* __restrict__ W0,
                                                  const float* __restrict__ W1,
                                                  const float* __restrict__ W2,
                                                  const float* __restrict__ W3,
                                                  u16* __restrict__ WT) {
  __shared__ float tile[64][65];
  const int blk = blockIdx.x & 255;
  const int sel = blockIdx.x >> 8;
  const float* W = (sel == 0) ? W0 : (sel == 1) ? W1 : (sel == 2) ? W2 : W3;
  u16* dst = WT + (size_t)sel * DIMN * DIMN;
  const int k0 = (blk >> 4) << 6;
  const int n0 = (blk & 15) << 6;
  const int tid = threadIdx.x;
  const int r = tid >> 6;
  const int c = tid & 63;
#pragma unroll
  for (int i = 0; i < 16; ++i) {
    int row = (i << 2) + r;
    tile[row][c] = W[(size_t)(k0 + row) * DIMN + n0 + c];
  }
  __syncthreads();
#pragma unroll
  for (int i = 0; i < 16; ++i) {
    int row = (i << 2) + r;
    dst[(size_t)(n0 + row) * DIMN + k0 + c] = f2bf(tile[c][row]);
  }
}

// --------------------------- x cast ----------------------------------------
__global__ __launch_bounds__(256) void cvt_x_kern(const float* __restrict__ x,
                                                  u16* __restrict__ xb) {
  size_t i = ((size_t)blockIdx.x * 256 + threadIdx.x) * 4;
  f32x4 v = *(const f32x4*)(x + i);
  s16x4 o;
  o.x = (short)f2bf(v.x); o.y = (short)f2bf(v.y);
  o.z = (short)f2bf(v.z); o.w = (short)f2bf(v.w);
  *(s16x4*)(xb + i) = o;
}

// --------------------------- 256x256 relaxed 4-phase bf16 GEMM --------------
// C[M][N] = A[M][1024] * Bt[N][1024]^T.
// MODE 0: N=3072 fused QKV -> q (softmax64), k (elu+1), v  (all bf16)
// MODE 1: N=1024 -> f32 out + bias
// 512 threads = 8 waves (2Mx4N); per-wave 128x64; BK=64 (two 32-K-halves).
// LDS 128KB dynamic: 2 buffers x [A-K0|A-K1|B-K0|B-K1] x 16KB.
// ONE barrier per phase; no lgkmcnt(0) wall (compiler emits fine-grained
// lgkm waits interleaving ds_read latency into the MFMA cluster).
// vmcnt(8) at end ph2/ph4: drains exactly kh1(t) / kh0(t+1) (ledger-checked).
template <int MODE>
__global__ __launch_bounds__(512, 2) void gemm256(
    const u16* __restrict__ A, const u16* __restrict__ Bt,
    u16* __restrict__ dq, u16* __restrict__ dk, u16* __restrict__ dv,
    float* __restrict__ dO, const float* __restrict__ bias) {
  constexpr int K = 1024;
  constexpr int BNT = (MODE == 0) ? 12 : 4;   // N / 256
  constexpr int NT = K / 64;                  // 16 K-tiles
  extern __shared__ char lds[];

  const int tid = threadIdx.x;
  const int l = tid & 63;
  const int w = tid >> 6;
  const int wm = w >> 2;           // 0..1
  const int wn = w & 3;            // 0..3

  const int nwg = (int)gridDim.x;
  const int bid = (int)blockIdx.x;
  const int swz = (bid & 7) * (nwg >> 3) + (bid >> 3);
  const int bm = swz / BNT, bn = swz % BNT;
  const size_t arow0 = (size_t)bm * 256;
  const size_t brow0 = (size_t)bn * 256;

  int lrow[2], lcol[2];
#pragma unroll
  for (int i = 0; i < 2; ++i) {
    int lg = swz16k(tid * 16 + i * 8192);
    lrow[i] = lg >> 6;
    lcol[i] = (lg & 63) >> 1;
  }

  const int fr = l & 15;
  const int kswz = (((l >> 4) << 4)) ^ ((((fr >> 1) & 3)) << 4);

  auto STAGE = [&](int matsel, int kh, int tt) {   // matsel 0=A 1=B
    const int kbase = (tt & (NT - 1)) * 64 + kh * 32;   // wrap tail (harmless)
#pragma unroll
    for (int i = 0; i < 2; ++i) {
      const u16* src = (matsel == 0)
          ? A  + (arow0 + (size_t)lrow[i]) * K + kbase + lcol[i]
          : Bt + (brow0 + (size_t)lrow[i]) * K + kbase + lcol[i];
      char* dst = lds + ((tt & 1) * 65536 + (matsel * 2 + kh) * 16384 +
                         i * 8192 + w * 1024);
      __builtin_amdgcn_global_load_lds(
          (__attribute__((address_space(1))) const void*)src,
          (__attribute__((address_space(3))) void*)dst, 16, 0, 0);
    }
  };
  auto LDA = [&](int buf, int kh, int rowb) -> s16x8 {
    return *(const s16x8*)(lds + buf * 65536 + kh * 16384 + rowb * 64 + kswz);
  };
  auto LDB = [&](int buf, int kh, int rowb) -> s16x8 {
    return *(const s16x8*)(lds + buf * 65536 + 32768 + kh * 16384 + rowb * 64 + kswz);
  };

  f32x4 acc[8][4];
#pragma unroll
  for (int i = 0; i < 8; ++i)
#pragma unroll
    for (int j = 0; j < 4; ++j) acc[i][j] = {0.f, 0.f, 0.f, 0.f};

  // prologue: tile0 full, tile1 K0; drain tile0-K0 (12 outstanding -> 8)
  STAGE(0, 0, 0); STAGE(1, 0, 0); STAGE(0, 1, 0); STAGE(1, 1, 0);
  STAGE(0, 0, 1); STAGE(1, 0, 1);
  asm volatile("s_waitcnt vmcnt(8)" ::: "memory");
  __builtin_amdgcn_sched_barrier(0);
  __builtin_amdgcn_s_barrier();

  const int amb = wm * 128;
  const int bnb = wn * 64;
  s16x8 af[4], bfr[4];

  for (int t = 0; t < NT; ++t) {
    const int buf = t & 1;
    // ---- phase 1: kh0, mi 0-3 x ni 0-3; stage A-K1(t+1) --------------------
    __builtin_amdgcn_sched_barrier(0);
#pragma unroll
    for (int i = 0; i < 4; ++i) af[i]  = LDA(buf, 0, amb + i * 16 + fr);
#pragma unroll
    for (int i = 0; i < 4; ++i) bfr[i] = LDB(buf, 0, bnb + i * 16 + fr);
    STAGE(0, 1, t + 1);
    __builtin_amdgcn_s_setprio(1);
#pragma unroll
    for (int mi = 0; mi < 4; ++mi)
#pragma unroll
      for (int ni = 0; ni < 4; ++ni)
        acc[mi][ni] = __builtin_amdgcn_mfma_f32_16x16x32_bf16(
            af[mi], bfr[ni], acc[mi][ni], 0, 0, 0);
    __builtin_amdgcn_s_setprio(0);
    __builtin_amdgcn_s_barrier();
    // ---- phase 2: kh0, mi 4-7 (reuse B); stage B-K1(t+1); drain kh1(t) -----
    __builtin_amdgcn_sched_barrier(0);
#pragma unroll
    for (int i = 0; i < 4; ++i) af[i] = LDA(buf, 0, amb + (4 + i) * 16 + fr);
    STAGE(1, 1, t + 1);
    __builtin_amdgcn_s_setprio(1);
#pragma unroll
    for (int mi = 0; mi < 4; ++mi)
#pragma unroll
      for (int ni = 0; ni < 4; ++ni)
        acc[4 + mi][ni] = __builtin_amdgcn_mfma_f32_16x16x32_bf16(
            af[mi], bfr[ni], acc[4 + mi][ni], 0, 0, 0);
    __builtin_amdgcn_s_setprio(0);
    asm volatile("s_waitcnt vmcnt(8)" ::: "memory");
    __builtin_amdgcn_sched_barrier(0);
    __builtin_amdgcn_s_barrier();
    // ---- phase 3: kh1, mi 0-3 x ni 0-3; stage A-K0(t+2) --------------------
    __builtin_amdgcn_sched_barrier(0);
#pragma unroll
    for (int i = 0; i < 4; ++i) af[i]  = LDA(buf, 1, amb + i * 16 + fr);
#pragma unroll
    for (int i = 0; i < 4; ++i) bfr[i] = LDB(buf, 1, bnb + i * 16 + fr);
    STAGE(0, 0, t + 2);
    __builtin_amdgcn_s_setprio(1);
#pragma unroll
    for (int mi = 0; mi < 4; ++mi)
#pragma unroll
      for (int ni = 0; ni < 4; ++ni)
        acc[mi][ni] = __builtin_amdgcn_mfma_f32_16x16x32_bf16(
            af[mi], bfr[ni], acc[mi][ni], 0, 0, 0);
    __builtin_amdgcn_s_setprio(0);
    __builtin_amdgcn_s_barrier();
    // ---- phase 4: kh1, mi 4-7 (reuse B); stage B-K0(t+2); drain kh0(t+1) ---
    __builtin_amdgcn_sched_barrier(0);
#pragma unroll
    for (int i = 0; i < 4; ++i) af[i] = LDA(buf, 1, amb + (4 + i) * 16 + fr);
    STAGE(1, 0, t + 2);
    __builtin_amdgcn_s_setprio(1);
#pragma unroll
    for (int mi = 0; mi < 4; ++mi)
#pragma unroll
      for (int ni = 0; ni < 4; ++ni)
        acc[4 + mi][ni] = __builtin_amdgcn_mfma_f32_16x16x32_bf16(
            af[mi], bfr[ni], acc[4 + mi][ni], 0, 0, 0);
    __builtin_amdgcn_s_setprio(0);
    asm volatile("s_waitcnt vmcnt(8)" ::: "memory");
    __builtin_amdgcn_sched_barrier(0);
    __builtin_amdgcn_s_barrier();
  }

  // ---- epilogue: drain in-flight staging, then LDS-stage C for coalesced IO
  asm volatile("s_waitcnt vmcnt(0)" ::: "memory");
  __builtin_amdgcn_sched_barrier(0);
  __builtin_amdgcn_s_barrier();

  const int r0 = (l >> 4) << 2;
  const int c0 = l & 15;
  if constexpr (MODE == 0) {
    // stage bf16 [256][256] in LDS, XOR-swizzled (4 disjoint bank-octets)
    u16* lt = (u16*)lds;
    const int mat = bn >> 2;                        // 0=q 1=k 2=v
    u16* dst = (mat == 0) ? dq : ((mat == 1) ? dk : dv);
    if (mat == 0) {
#pragma unroll
      for (int mi = 0; mi < 8; ++mi) {
#pragma unroll
        for (int j = 0; j < 4; ++j) {
          float v0 = acc[mi][0][j], v1 = acc[mi][1][j];
          float v2 = acc[mi][2][j], v3 = acc[mi][3][j];
          float m = fmaxf(fmaxf(v0, v1), fmaxf(v2, v3));
#pragma unroll
          for (int off = 1; off < 16; off <<= 1) m = fmaxf(m, __shfl_xor(m, off));
          float e0 = __expf(v0 - m), e1 = __expf(v1 - m);
          float e2 = __expf(v2 - m), e3 = __expf(v3 - m);
          float s = e0 + e1 + e2 + e3;
#pragma unroll
          for (int off = 1; off < 16; off <<= 1) s += __shfl_xor(s, off);
          float inv = 1.f / s;
          const int row = wm * 128 + mi * 16 + r0 + j;
          const int sxr = ((row >> 2) & 7) << 4;
          const int cb = wn * 64 + c0;
          lt[row * 256 + ((cb) ^ sxr)]      = f2bf(e0 * inv);
          lt[row * 256 + ((cb + 16) ^ sxr)] = f2bf(e1 * inv);
          lt[row * 256 + ((cb + 32) ^ sxr)] = f2bf(e2 * inv);
          lt[row * 256 + ((cb + 48) ^ sxr)] = f2bf(e3 * inv);
        }
      }
    } else {
#pragma unroll
      for (int mi = 0; mi < 8; ++mi)
#pragma unroll
        for (int ni = 0; ni < 4; ++ni)
#pragma unroll
          for (int j = 0; j < 4; ++j) {
            const int row = wm * 128 + mi * 16 + r0 + j;
            const int col = wn * 64 + ni * 16 + c0;
            float v = acc[mi][ni][j];
            float r = (mat == 1) ? (v > 0.f ? v + 1.f : __expf(v)) : v;
            lt[row * 256 + (col ^ (((row >> 2) & 7) << 4))] = f2bf(r);
          }
    }
    __builtin_amdgcn_s_barrier();
    const size_t gcb = (size_t)(bn & 3) * 256;
#pragma unroll
    for (int i = 0; i < 16; ++i) {
      const int cid = tid + i * 512;
      const int r = cid >> 5;
      const int g = (cid & 31) * 8;
      const int pc = g ^ (((r >> 2) & 7) << 4);
      s16x8 vv = *(const s16x8*)&lt[r * 256 + pc];
      *(s16x8*)&dst[(arow0 + r) * DIMN + gcb + g] = vv;
    }
  } else {
    // f32 [128][256] in LDS (two rounds by wm), 2-way-max bank pattern
    float* lf = (float*)lds;
#pragma unroll
    for (int half = 0; half < 2; ++half) {
      if (wm == half) {
#pragma unroll
        for (int mi = 0; mi < 8; ++mi)
#pragma unroll
          for (int ni = 0; ni < 4; ++ni) {
            const int col = wn * 64 + ni * 16 + c0;
            const float bv = bias[brow0 + col];
#pragma unroll
            for (int j = 0; j < 4; ++j) {
              const int row = mi * 16 + r0 + j;
              lf[row * 256 + (col ^ (((row >> 2) & 1) << 4))] =
                  acc[mi][ni][j] + bv;
            }
          }
      }
      __builtin_amdgcn_s_barrier();
#pragma unroll
      for (int i = 0; i < 16; ++i) {
        const int cid = tid + i * 512;
        const int r = cid >> 6;
        const int g = (cid & 63) * 4;
        const int pc = g ^ (((r >> 2) & 1) << 4);
        f32x4 vv = *(const f32x4*)&lf[r * 256 + pc];
        *(f32x4*)&dO[(arow0 + half * 128 + r) * DIMN + brow0 + g] = vv;
      }
      __builtin_amdgcn_s_barrier();
    }
  }
}

// --------------------------- per-bucket context: C_u = k_u^T v_u ------------
__global__ __launch_bounds__(256) void ctx_bucket_kern(const u16* __restrict__ kb,
                                                       const u16* __restrict__ vb,
                                                       float* __restrict__ ctx,
                                                       float* __restrict__ ksum) {
  __shared__ float kl[4096];
  __shared__ float vl[4096];
  const int blk = blockIdx.x;
  const int u = blk & 63;
  const int bh = blk >> 6;
  const int b = bh >> 4, h = bh & 15;
  const size_t rowbase = (size_t)b * T_LEN + (size_t)u * 64;
  const int tid = threadIdx.x;
#pragma unroll
  for (int i = 0; i < 16; ++i) {
    int idx = i * 256 + tid;
    int n = idx >> 6, d = idx & 63;
    size_t g = (rowbase + n) * DIMN + (size_t)h * 64 + d;
    kl[idx] = bf2f(kb[g]);
    vl[idx] = bf2f(vb[g]);
  }
  __syncthreads();
  const int dq = (tid & 15) << 2;
  const int eq = (tid >> 4) << 2;
  float a[4][4] = {};
  float ks[4] = {};
  for (int n = 0; n < 64; ++n) {
    f32x4 kv = *(const f32x4*)&kl[n * 64 + dq];
    f32x4 vv = *(const f32x4*)&vl[n * 64 + eq];
#pragma unroll
    for (int i = 0; i < 4; ++i) {
      ks[i] += kv[i];
#pragma unroll
      for (int j = 0; j < 4; ++j) a[i][j] += kv[i] * vv[j];
    }
  }
  const size_t cbase = (size_t)blk * 4096;
#pragma unroll
  for (int i = 0; i < 4; ++i) {
    f32x4 o = {a[i][0], a[i][1], a[i][2], a[i][3]};
    *(f32x4*)&ctx[cbase + (size_t)(dq + i) * 64 + eq] = o;
  }
  if ((tid >> 4) == 0) {
    f32x4 o = {ks[0], ks[1], ks[2], ks[3]};
    *(f32x4*)&ksum[(size_t)blk * 64 + dq] = o;
  }
}

// --------------------------- cumsum over u + normalize + shift, in place ----
__global__ __launch_bounds__(256) void ctx_cumnorm_kern(float* __restrict__ ctx,
                                                        const float* __restrict__ ksum) {
  const int tid = blockIdx.x * 256 + threadIdx.x;   // 262144 chains
  const int bh = tid >> 12;
  const int rem = tid & 4095;
  const int d = rem >> 6;
  const int e = rem & 63;
  float c = 0.f, accK = 0.f;
  for (int u = 0; u < 64; ++u) {
    const size_t base = ((size_t)(bh * 64 + u)) * 4096 + (size_t)d * 64 + e;
    float cv = ctx[base];
    float kk = ksum[(size_t)(bh * 64 + u) * 64 + d];
    float o = (u == 0) ? 0.f : c / (accK + 1e-6f);
    ctx[base] = o;
    c += cv; accK += kk;
  }
}

// --------------------------- per-bucket attn: q_u @ ctx_u -------------------
__global__ __launch_bounds__(256) void attn_bucket_kern(const u16* __restrict__ qb,
                                                        const float* __restrict__ ctx,
                                                        u16* __restrict__ attn) {
  __shared__ float qT[64 * 68];
  __shared__ float cl[4096];
  const int blk = blockIdx.x;
  const int u = blk & 63;
  const int bh = blk >> 6;
  const int b = bh >> 4, h = bh & 15;
  const size_t rowbase = (size_t)b * T_LEN + (size_t)u * 64;
  const int tid = threadIdx.x;
  const size_t cbase = (size_t)blk * 4096;
#pragma unroll
  for (int i = 0; i < 16; ++i) {
    int idx = i * 256 + tid;
    int n = idx >> 6, d = idx & 63;
    qT[d * 68 + n] = bf2f(qb[(rowbase + n) * DIMN + (size_t)h * 64 + d]);
    cl[idx] = ctx[cbase + idx];
  }
  __syncthreads();
  const int nq = (tid & 15) << 2;
  const int eq = (tid >> 4) << 2;
  float a[4][4] = {};
  for (int d = 0; d < 64; ++d) {
    f32x4 qv = *(const f32x4*)&qT[d * 68 + nq];
    f32x4 cv = *(const f32x4*)&cl[d * 64 + eq];
#pragma unroll
    for (int i = 0; i < 4; ++i)
#pragma unroll
      for (int j = 0; j < 4; ++j) a[i][j] += qv[i] * cv[j];
  }
#pragma unroll
  for (int i = 0; i < 4; ++i) {
    s16x4 o;
    o.x = (short)f2bf(a[i][0]); o.y = (short)f2bf(a[i][1]);
    o.z = (short)f2bf(a[i][2]); o.w = (short)f2bf(a[i][3]);
    *(s16x4*)&attn[(rowbase + nq + i) * DIMN + (size_t)h * 64 + eq] = o;
  }
}

// ---------------------------------------------------------------------------
extern "C" void kernel_launch(void* const* d_in, const int* in_sizes, int n_in,
                              void* d_out, int out_size, void* d_ws, size_t ws_size,
                              hipStream_t stream) {
  const float* x  = (const float*)d_in[0];
  const float* Wq = (const float*)d_in[1];
  const float* Wk = (const float*)d_in[2];
  const float* Wv = (const float*)d_in[3];
  const float* Wo = (const float*)d_in[4];
  const float* bo = (const float*)d_in[5];
  float* out = (float*)d_out;

  constexpr size_t SZ_XB = (size_t)MROWS * DIMN * 2;
  constexpr size_t SZ_WT = (size_t)DIMN * DIMN * 2;
  constexpr size_t SZ_CTX = (size_t)NB * NHEAD * 64 * 64 * 64 * 4;
  char* ws = (char*)d_ws;
  u16*   xb   = (u16*)(ws);
  u16*   wqT  = (u16*)(ws + SZ_XB);          // wq/wk/wv/wo contiguous
  u16*   woT  = (u16*)(ws + SZ_XB + 3 * SZ_WT);
  u16*   qb   = (u16*)(ws + SZ_XB + 4 * SZ_WT);
  u16*   kb   = (u16*)(ws + 2 * SZ_XB + 4 * SZ_WT);
  u16*   vb   = (u16*)(ws + 3 * SZ_XB + 4 * SZ_WT);
  float* ctx  = (float*)(ws + 4 * SZ_XB + 4 * SZ_WT);
  float* ksum = (float*)(ws + 4 * SZ_XB + 4 * SZ_WT + SZ_CTX);
  u16*   attn = xb;  // xb dead after QKV GEMM

  (void)hipFuncSetAttribute((const void*)gemm256<0>,
                            hipFuncAttributeMaxDynamicSharedMemorySize, 131072);
  (void)hipFuncSetAttribute((const void*)gemm256<1>,
                            hipFuncAttributeMaxDynamicSharedMemorySize, 131072);

  cvt_w_kern<<<1024, 256, 0, stream>>>(Wq, Wk, Wv, Wo, wqT);
  cvt_x_kern<<<MROWS * DIMN / 4 / 256, 256, 0, stream>>>(x, xb);

  // fused QKV: N = 3072, grid 64 x 12 = 768
  gemm256<0><<<768, 512, 131072, stream>>>(xb, wqT, qb, kb, vb, nullptr, nullptr);

  ctx_bucket_kern<<<NB * NHEAD * 64, 256, 0, stream>>>(kb, vb, ctx, ksum);
  ctx_cumnorm_kern<<<1024, 256, 0, stream>>>(ctx, ksum);
  attn_bucket_kern<<<NB * NHEAD * 64, 256, 0, stream>>>(qb, ctx, attn);

  // output: N = 1024, grid 64 x 4 = 256
  gemm256<1><<<256, 512, 131072, stream>>>(attn, woT, nullptr, nullptr, nullptr, out, bo);
}

// Round 5
// 280.516 us; speedup vs baseline: 1.4761x; 1.0137x over previous
//
#include <hip/hip_runtime.h>

// ---------------------------------------------------------------------------
// LinearSelfAttention: B=4 T=4096 DIM=1024 H=16 E=64 BUCKET=64 U=64
// ---------------------------------------------------------------------------

#define T_LEN 4096
#define DIMN  1024
#define NHEAD 16
#define NB    4
#define MROWS (NB * T_LEN)   // 16384

typedef float f32x4 __attribute__((ext_vector_type(4)));
typedef short s16x8 __attribute__((ext_vector_type(8)));
typedef short s16x4 __attribute__((ext_vector_type(4)));
using u16 = unsigned short;

__device__ __forceinline__ u16 f2bf(float f) {
  unsigned int u = __float_as_uint(f);
  u += 0x7fffu + ((u >> 16) & 1u);   // RNE
  return (u16)(u >> 16);
}
__device__ __forceinline__ float bf2f(u16 h) {
  return __uint_as_float(((unsigned int)h) << 16);
}
// involution swizzle within a 16KB half-slot ([256 rows][32 bf16] = row*64B)
__device__ __forceinline__ int swz16k(int off) {
  return off ^ (((off >> 7) & 3) << 4);
}

// --------------------------- weight transpose+cast (all 4 in one launch) ----
__global__ __launch_bounds__(256) void cvt_w_kern(const float* __restrict__ W0,
                                                  const float* __restrict__ W1,
                                                  const float* __restrict__ W2,
                                                  const float* __restrict__ W3,
                                                  u16* __restrict__ WT) {
  __shared__ float tile[64][65];
  const int blk = blockIdx.x & 255;
  const int sel = blockIdx.x >> 8;
  const float* W = (sel == 0) ? W0 : (sel == 1) ? W1 : (sel == 2) ? W2 : W3;
  u16* dst = WT + (size_t)sel * DIMN * DIMN;
  const int k0 = (blk >> 4) << 6;
  const int n0 = (blk & 15) << 6;
  const int tid = threadIdx.x;
  const int r = tid >> 6;
  const int c = tid & 63;
#pragma unroll
  for (int i = 0; i < 16; ++i) {
    int row = (i << 2) + r;
    tile[row][c] = W[(size_t)(k0 + row) * DIMN + n0 + c];
  }
  __syncthreads();
#pragma unroll
  for (int i = 0; i < 16; ++i) {
    int row = (i << 2) + r;
    dst[(size_t)(n0 + row) * DIMN + k0 + c] = f2bf(tile[c][row]);
  }
}

// --------------------------- x cast ----------------------------------------
__global__ __launch_bounds__(256) void cvt_x_kern(const float* __restrict__ x,
                                                  u16* __restrict__ xb) {
  size_t i = ((size_t)blockIdx.x * 256 + threadIdx.x) * 4;
  f32x4 v = *(const f32x4*)(x + i);
  s16x4 o;
  o.x = (short)f2bf(v.x); o.y = (short)f2bf(v.y);
  o.z = (short)f2bf(v.z); o.w = (short)f2bf(v.w);
  *(s16x4*)(xb + i) = o;
}

// --------------------------- 256x256 reg-pipelined 4-phase bf16 GEMM --------
// C[M][N] = A[M][1024] * Bt[N][1024]^T.
// MODE 0: N=3072 fused QKV -> q (softmax64), k (elu+1), v  (all bf16)
// MODE 1: N=1024 -> f32 out + bias
// 512 threads = 8 waves (2Mx4N); per-wave 128x64; BK=64 (two 32-K-halves).
// LDS 128KB: 2 buffers x [A-K0|A-K1|B-K0|B-K1] x 16KB.
// KEY (R5): each phase issues ds_reads for the NEXT phase's fragments
// (static double-buffered reg sets afA/afB, bfA/bfB), so the compiler's
// dependency-driven lgkmcnt(N) leaves them in flight during this phase's
// MFMA cluster -> LDS reads overlap MFMA. vmcnt(8) sits BEFORE the
// read-aheads it feeds (ph2: kh1(t); ph4: kh0(t+1)) -- ledger-checked.
template <int MODE>
__global__ __launch_bounds__(512, 2) void gemm256(
    const u16* __restrict__ A, const u16* __restrict__ Bt,
    u16* __restrict__ dq, u16* __restrict__ dk, u16* __restrict__ dv,
    float* __restrict__ dO, const float* __restrict__ bias) {
  constexpr int K = 1024;
  constexpr int BNT = (MODE == 0) ? 12 : 4;   // N / 256
  constexpr int NT = K / 64;                  // 16 K-tiles
  extern __shared__ char lds[];

  const int tid = threadIdx.x;
  const int l = tid & 63;
  const int w = tid >> 6;
  const int wm = w >> 2;           // 0..1
  const int wn = w & 3;            // 0..3

  const int nwg = (int)gridDim.x;
  const int bid = (int)blockIdx.x;
  const int swz = (bid & 7) * (nwg >> 3) + (bid >> 3);
  const int bm = swz / BNT, bn = swz % BNT;
  const size_t arow0 = (size_t)bm * 256;
  const size_t brow0 = (size_t)bn * 256;

  int lrow[2], lcol[2];
#pragma unroll
  for (int i = 0; i < 2; ++i) {
    int lg = swz16k(tid * 16 + i * 8192);
    lrow[i] = lg >> 6;
    lcol[i] = (lg & 63) >> 1;
  }

  const int fr = l & 15;
  const int kswz = (((l >> 4) << 4)) ^ ((((fr >> 1) & 3)) << 4);

  auto STAGE = [&](int matsel, int kh, int tt) {   // matsel 0=A 1=B
    const int kbase = (tt & (NT - 1)) * 64 + kh * 32;   // wrap tail (harmless)
#pragma unroll
    for (int i = 0; i < 2; ++i) {
      const u16* src = (matsel == 0)
          ? A  + (arow0 + (size_t)lrow[i]) * K + kbase + lcol[i]
          : Bt + (brow0 + (size_t)lrow[i]) * K + kbase + lcol[i];
      char* dst = lds + ((tt & 1) * 65536 + (matsel * 2 + kh) * 16384 +
                         i * 8192 + w * 1024);
      __builtin_amdgcn_global_load_lds(
          (__attribute__((address_space(1))) const void*)src,
          (__attribute__((address_space(3))) void*)dst, 16, 0, 0);
    }
  };
  auto LDA = [&](int buf, int kh, int rowb) -> s16x8 {
    return *(const s16x8*)(lds + buf * 65536 + kh * 16384 + rowb * 64 + kswz);
  };
  auto LDB = [&](int buf, int kh, int rowb) -> s16x8 {
    return *(const s16x8*)(lds + buf * 65536 + 32768 + kh * 16384 + rowb * 64 + kswz);
  };

  f32x4 acc[8][4];
#pragma unroll
  for (int i = 0; i < 8; ++i)
#pragma unroll
    for (int j = 0; j < 4; ++j) acc[i][j] = {0.f, 0.f, 0.f, 0.f};

  // prologue: tile0 full, tile1 K0; drain tile0-K0 (12 outstanding -> 8)
  STAGE(0, 0, 0); STAGE(1, 0, 0); STAGE(0, 1, 0); STAGE(1, 1, 0);
  STAGE(0, 0, 1); STAGE(1, 0, 1);
  asm volatile("s_waitcnt vmcnt(8)" ::: "memory");
  __builtin_amdgcn_sched_barrier(0);
  __builtin_amdgcn_s_barrier();

  const int amb = wm * 128;
  const int bnb = wn * 64;
  s16x8 afA[4], afB[4], bfA[4], bfB[4];

  // pre-read ph1(t=0) fragments: kh0 of tile0
#pragma unroll
  for (int i = 0; i < 4; ++i) afA[i] = LDA(0, 0, amb + i * 16 + fr);
#pragma unroll
  for (int i = 0; i < 4; ++i) bfA[i] = LDB(0, 0, bnb + i * 16 + fr);

#define MFMA_BLK(ACCOFF, AF, BF)                                              \
  __builtin_amdgcn_s_setprio(1);                                              \
  _Pragma("unroll")                                                           \
  for (int mi = 0; mi < 4; ++mi)                                              \
    _Pragma("unroll")                                                         \
    for (int ni = 0; ni < 4; ++ni)                                            \
      acc[(ACCOFF) + mi][ni] = __builtin_amdgcn_mfma_f32_16x16x32_bf16(       \
          AF[mi], BF[ni], acc[(ACCOFF) + mi][ni], 0, 0, 0);                   \
  __builtin_amdgcn_s_setprio(0);

#define PHASES(BUF, T)                                                        \
  {                                                                           \
    const int buf = (BUF);                                                    \
    const int t = (T);                                                        \
    /* ph1: MFMA kh0 mi0-3 (afA x bfA); read afB=kh0 mi4-7; stage A-K1(t+1)*/ \
    STAGE(0, 1, t + 1);                                                       \
    _Pragma("unroll")                                                         \
    for (int i = 0; i < 4; ++i) afB[i] = LDA(buf, 0, amb + (4 + i) * 16 + fr);\
    MFMA_BLK(0, afA, bfA)                                                     \
    __builtin_amdgcn_s_barrier();                                             \
    /* ph2: MFMA kh0 mi4-7 (afB x bfA); vmcnt drains kh1(t); read afA,bfB */  \
    STAGE(1, 1, t + 1);                                                       \
    asm volatile("s_waitcnt vmcnt(8)" ::: "memory");                          \
    __builtin_amdgcn_sched_barrier(0);                                        \
    _Pragma("unroll")                                                         \
    for (int i = 0; i < 4; ++i) afA[i] = LDA(buf, 1, amb + i * 16 + fr);      \
    _Pragma("unroll")                                                         \
    for (int i = 0; i < 4; ++i) bfB[i] = LDB(buf, 1, bnb + i * 16 + fr);      \
    MFMA_BLK(4, afB, bfA)                                                     \
    __builtin_amdgcn_s_barrier();                                             \
    /* ph3: MFMA kh1 mi0-3 (afA x bfB); read afB=kh1 mi4-7; stage A-K0(t+2)*/ \
    STAGE(0, 0, t + 2);                                                       \
    _Pragma("unroll")                                                         \
    for (int i = 0; i < 4; ++i) afB[i] = LDA(buf, 1, amb + (4 + i) * 16 + fr);\
    MFMA_BLK(0, afA, bfB)                                                     \
    __builtin_amdgcn_s_barrier();                                             \
    /* ph4: MFMA kh1 mi4-7 (afB x bfB); vmcnt drains kh0(t+1); read next */   \
    STAGE(1, 0, t + 2);                                                       \
    asm volatile("s_waitcnt vmcnt(8)" ::: "memory");                          \
    __builtin_amdgcn_sched_barrier(0);                                        \
    _Pragma("unroll")                                                         \
    for (int i = 0; i < 4; ++i) afA[i] = LDA(buf ^ 1, 0, amb + i * 16 + fr);  \
    _Pragma("unroll")                                                         \
    for (int i = 0; i < 4; ++i) bfA[i] = LDB(buf ^ 1, 0, bnb + i * 16 + fr);  \
    MFMA_BLK(4, afB, bfB)                                                     \
    __builtin_amdgcn_s_barrier();                                             \
  }

#pragma unroll 1
  for (int th = 0; th < NT / 2; ++th) {
    PHASES(0, 2 * th)
    PHASES(1, 2 * th + 1)
  }
#undef PHASES
#undef MFMA_BLK

  // ---------------- epilogue: C row = (lane>>4)*4+j, col = lane&15 ----------
  const int r0 = (l >> 4) << 2;
  const int c0 = l & 15;
  if constexpr (MODE == 0) {
    const int mat = bn >> 2;                        // 0=q 1=k 2=v
    u16* dst = (mat == 0) ? dq : ((mat == 1) ? dk : dv);
    const size_t colbase = (size_t)(bn & 3) * 256 + (size_t)wn * 64;
    if (mat == 0) {
      // fused per-head softmax over the wave's 64 cols (= one head)
#pragma unroll
      for (int mi = 0; mi < 8; ++mi) {
#pragma unroll
        for (int j = 0; j < 4; ++j) {
          float v0 = acc[mi][0][j], v1 = acc[mi][1][j];
          float v2 = acc[mi][2][j], v3 = acc[mi][3][j];
          float m = fmaxf(fmaxf(v0, v1), fmaxf(v2, v3));
#pragma unroll
          for (int off = 1; off < 16; off <<= 1) m = fmaxf(m, __shfl_xor(m, off));
          float e0 = __expf(v0 - m), e1 = __expf(v1 - m);
          float e2 = __expf(v2 - m), e3 = __expf(v3 - m);
          float s = e0 + e1 + e2 + e3;
#pragma unroll
          for (int off = 1; off < 16; off <<= 1) s += __shfl_xor(s, off);
          float inv = 1.f / s;
          const size_t row = arow0 + wm * 128 + mi * 16 + r0 + j;
          u16* p = dst + row * DIMN + colbase + c0;
          p[0]  = f2bf(e0 * inv); p[16] = f2bf(e1 * inv);
          p[32] = f2bf(e2 * inv); p[48] = f2bf(e3 * inv);
        }
      }
    } else {
#pragma unroll
      for (int mi = 0; mi < 8; ++mi)
#pragma unroll
        for (int ni = 0; ni < 4; ++ni)
#pragma unroll
          for (int j = 0; j < 4; ++j) {
            const size_t row = arow0 + wm * 128 + mi * 16 + r0 + j;
            float v = acc[mi][ni][j];
            float r = (mat == 1) ? (v > 0.f ? v + 1.f : __expf(v)) : v;
            dst[row * DIMN + colbase + ni * 16 + c0] = f2bf(r);
          }
    }
  } else {
    // drain staging before reusing LDS for the C tile
    asm volatile("s_waitcnt vmcnt(0)" ::: "memory");
    __builtin_amdgcn_sched_barrier(0);
    __builtin_amdgcn_s_barrier();
    float* lf = (float*)lds;
#pragma unroll
    for (int half = 0; half < 2; ++half) {
      if (wm == half) {
#pragma unroll
        for (int mi = 0; mi < 8; ++mi)
#pragma unroll
          for (int ni = 0; ni < 4; ++ni) {
            const int col = wn * 64 + ni * 16 + c0;
            const float bv = bias[brow0 + col];
#pragma unroll
            for (int j = 0; j < 4; ++j) {
              const int row = mi * 16 + r0 + j;
              lf[row * 256 + (col ^ (((row >> 2) & 1) << 4))] =
                  acc[mi][ni][j] + bv;
            }
          }
      }
      __builtin_amdgcn_s_barrier();
#pragma unroll
      for (int i = 0; i < 16; ++i) {
        const int cid = tid + i * 512;
        const int r = cid >> 6;
        const int g = (cid & 63) * 4;
        const int pc = g ^ (((r >> 2) & 1) << 4);
        f32x4 vv = *(const f32x4*)&lf[r * 256 + pc];
        *(f32x4*)&dO[(arow0 + half * 128 + r) * DIMN + brow0 + g] = vv;
      }
      __builtin_amdgcn_s_barrier();
    }
  }
}

// --------------------------- per-bucket context: C_u = k_u^T v_u ------------
__global__ __launch_bounds__(256) void ctx_bucket_kern(const u16* __restrict__ kb,
                                                       const u16* __restrict__ vb,
                                                       float* __restrict__ ctx,
                                                       float* __restrict__ ksum) {
  __shared__ float kl[4096];
  __shared__ float vl[4096];
  const int blk = blockIdx.x;
  const int u = blk & 63;
  const int bh = blk >> 6;
  const int b = bh >> 4, h = bh & 15;
  const size_t rowbase = (size_t)b * T_LEN + (size_t)u * 64;
  const int tid = threadIdx.x;
#pragma unroll
  for (int i = 0; i < 16; ++i) {
    int idx = i * 256 + tid;
    int n = idx >> 6, d = idx & 63;
    size_t g = (rowbase + n) * DIMN + (size_t)h * 64 + d;
    kl[idx] = bf2f(kb[g]);
    vl[idx] = bf2f(vb[g]);
  }
  __syncthreads();
  const int dq = (tid & 15) << 2;
  const int eq = (tid >> 4) << 2;
  float a[4][4] = {};
  float ks[4] = {};
  for (int n = 0; n < 64; ++n) {
    f32x4 kv = *(const f32x4*)&kl[n * 64 + dq];
    f32x4 vv = *(const f32x4*)&vl[n * 64 + eq];
#pragma unroll
    for (int i = 0; i < 4; ++i) {
      ks[i] += kv[i];
#pragma unroll
      for (int j = 0; j < 4; ++j) a[i][j] += kv[i] * vv[j];
    }
  }
  const size_t cbase = (size_t)blk * 4096;
#pragma unroll
  for (int i = 0; i < 4; ++i) {
    f32x4 o = {a[i][0], a[i][1], a[i][2], a[i][3]};
    *(f32x4*)&ctx[cbase + (size_t)(dq + i) * 64 + eq] = o;
  }
  if ((tid >> 4) == 0) {
    f32x4 o = {ks[0], ks[1], ks[2], ks[3]};
    *(f32x4*)&ksum[(size_t)blk * 64 + dq] = o;
  }
}

// --------------------------- cumsum over u + normalize + shift, in place ----
__global__ __launch_bounds__(256) void ctx_cumnorm_kern(float* __restrict__ ctx,
                                                        const float* __restrict__ ksum) {
  const int tid = blockIdx.x * 256 + threadIdx.x;   // 262144 chains
  const int bh = tid >> 12;
  const int rem = tid & 4095;
  const int d = rem >> 6;
  const int e = rem & 63;
  float c = 0.f, accK = 0.f;
  for (int u = 0; u < 64; ++u) {
    const size_t base = ((size_t)(bh * 64 + u)) * 4096 + (size_t)d * 64 + e;
    float cv = ctx[base];
    float kk = ksum[(size_t)(bh * 64 + u) * 64 + d];
    float o = (u == 0) ? 0.f : c / (accK + 1e-6f);
    ctx[base] = o;
    c += cv; accK += kk;
  }
}

// --------------------------- per-bucket attn: q_u @ ctx_u -------------------
__global__ __launch_bounds__(256) void attn_bucket_kern(const u16* __restrict__ qb,
                                                        const float* __restrict__ ctx,
                                                        u16* __restrict__ attn) {
  __shared__ float qT[64 * 68];
  __shared__ float cl[4096];
  const int blk = blockIdx.x;
  const int u = blk & 63;
  const int bh = blk >> 6;
  const int b = bh >> 4, h = bh & 15;
  const size_t rowbase = (size_t)b * T_LEN + (size_t)u * 64;
  const int tid = threadIdx.x;
  const size_t cbase = (size_t)blk * 4096;
#pragma unroll
  for (int i = 0; i < 16; ++i) {
    int idx = i * 256 + tid;
    int n = idx >> 6, d = idx & 63;
    qT[d * 68 + n] = bf2f(qb[(rowbase + n) * DIMN + (size_t)h * 64 + d]);
    cl[idx] = ctx[cbase + idx];
  }
  __syncthreads();
  const int nq = (tid & 15) << 2;
  const int eq = (tid >> 4) << 2;
  float a[4][4] = {};
  for (int d = 0; d < 64; ++d) {
    f32x4 qv = *(const f32x4*)&qT[d * 68 + nq];
    f32x4 cv = *(const f32x4*)&cl[d * 64 + eq];
#pragma unroll
    for (int i = 0; i < 4; ++i)
#pragma unroll
      for (int j = 0; j < 4; ++j) a[i][j] += qv[i] * cv[j];
  }
#pragma unroll
  for (int i = 0; i < 4; ++i) {
    s16x4 o;
    o.x = (short)f2bf(a[i][0]); o.y = (short)f2bf(a[i][1]);
    o.z = (short)f2bf(a[i][2]); o.w = (short)f2bf(a[i][3]);
    *(s16x4*)&attn[(rowbase + nq + i) * DIMN + (size_t)h * 64 + eq] = o;
  }
}

// ---------------------------------------------------------------------------
extern "C" void kernel_launch(void* const* d_in, const int* in_sizes, int n_in,
                              void* d_out, int out_size, void* d_ws, size_t ws_size,
                              hipStream_t stream) {
  const float* x  = (const float*)d_in[0];
  const float* Wq = (const float*)d_in[1];
  const float* Wk = (const float*)d_in[2];
  const float* Wv = (const float*)d_in[3];
  const float* Wo = (const float*)d_in[4];
  const float* bo = (const float*)d_in[5];
  float* out = (float*)d_out;

  constexpr size_t SZ_XB = (size_t)MROWS * DIMN * 2;
  constexpr size_t SZ_WT = (size_t)DIMN * DIMN * 2;
  constexpr size_t SZ_CTX = (size_t)NB * NHEAD * 64 * 64 * 64 * 4;
  char* ws = (char*)d_ws;
  u16*   xb   = (u16*)(ws);
  u16*   wqT  = (u16*)(ws + SZ_XB);          // wq/wk/wv/wo contiguous
  u16*   woT  = (u16*)(ws + SZ_XB + 3 * SZ_WT);
  u16*   qb   = (u16*)(ws + SZ_XB + 4 * SZ_WT);
  u16*   kb   = (u16*)(ws + 2 * SZ_XB + 4 * SZ_WT);
  u16*   vb   = (u16*)(ws + 3 * SZ_XB + 4 * SZ_WT);
  float* ctx  = (float*)(ws + 4 * SZ_XB + 4 * SZ_WT);
  float* ksum = (float*)(ws + 4 * SZ_XB + 4 * SZ_WT + SZ_CTX);
  u16*   attn = xb;  // xb dead after QKV GEMM

  (void)hipFuncSetAttribute((const void*)gemm256<0>,
                            hipFuncAttributeMaxDynamicSharedMemorySize, 131072);
  (void)hipFuncSetAttribute((const void*)gemm256<1>,
                            hipFuncAttributeMaxDynamicSharedMemorySize, 131072);

  cvt_w_kern<<<1024, 256, 0, stream>>>(Wq, Wk, Wv, Wo, wqT);
  cvt_x_kern<<<MROWS * DIMN / 4 / 256, 256, 0, stream>>>(x, xb);

  // fused QKV: N = 3072, grid 64 x 12 = 768
  gemm256<0><<<768, 512, 131072, stream>>>(xb, wqT, qb, kb, vb, nullptr, nullptr);

  ctx_bucket_kern<<<NB * NHEAD * 64, 256, 0, stream>>>(kb, vb, ctx, ksum);
  ctx_cumnorm_kern<<<1024, 256, 0, stream>>>(ctx, ksum);
  attn_bucket_kern<<<NB * NHEAD * 64, 256, 0, stream>>>(qb, ctx, attn);

  // output: N = 1024, grid 64 x 4 = 256
  gemm256<1><<<256, 512, 131072, stream>>>(attn, woT, nullptr, nullptr, nullptr, out, bo);
}

// Round 6
// 263.855 us; speedup vs baseline: 1.5693x; 1.0631x over previous
//
#include <hip/hip_runtime.h>

// ---------------------------------------------------------------------------
// LinearSelfAttention: B=4 T=4096 DIM=1024 H=16 E=64 BUCKET=64 U=64
// ---------------------------------------------------------------------------

#define T_LEN 4096
#define DIMN  1024
#define NHEAD 16
#define NB    4
#define MROWS (NB * T_LEN)   // 16384

typedef float f32x4 __attribute__((ext_vector_type(4)));
typedef short s16x8 __attribute__((ext_vector_type(8)));
typedef short s16x4 __attribute__((ext_vector_type(4)));
using u16 = unsigned short;

__device__ __forceinline__ u16 f2bf(float f) {
  unsigned int u = __float_as_uint(f);
  u += 0x7fffu + ((u >> 16) & 1u);   // RNE
  return (u16)(u >> 16);
}
__device__ __forceinline__ float bf2f(u16 h) {
  return __uint_as_float(((unsigned int)h) << 16);
}
// involution swizzle within a 16KB half-slot ([256 rows][32 bf16] = row*64B)
__device__ __forceinline__ int swz16k(int off) {
  return off ^ (((off >> 7) & 3) << 4);
}

// ------------------- fused weight transpose+cast AND x cast ----------------
// blocks [0,1024): W transpose tiles; blocks [1024, 17408): x cast.
__global__ __launch_bounds__(256) void cvt_all_kern(const float* __restrict__ x,
                                                    const float* __restrict__ W0,
                                                    const float* __restrict__ W1,
                                                    const float* __restrict__ W2,
                                                    const float* __restrict__ W3,
                                                    u16* __restrict__ WT,
                                                    u16* __restrict__ xb) {
  __shared__ float tile[64][65];
  const int tid = threadIdx.x;
  if (blockIdx.x < 1024) {
    const int blk = blockIdx.x & 255;
    const int sel = blockIdx.x >> 8;
    const float* W = (sel == 0) ? W0 : (sel == 1) ? W1 : (sel == 2) ? W2 : W3;
    u16* dst = WT + (size_t)sel * DIMN * DIMN;
    const int k0 = (blk >> 4) << 6;
    const int n0 = (blk & 15) << 6;
    const int r = tid >> 6;
    const int c = tid & 63;
#pragma unroll
    for (int i = 0; i < 16; ++i) {
      int row = (i << 2) + r;
      tile[row][c] = W[(size_t)(k0 + row) * DIMN + n0 + c];
    }
    __syncthreads();
#pragma unroll
    for (int i = 0; i < 16; ++i) {
      int row = (i << 2) + r;
      dst[(size_t)(n0 + row) * DIMN + k0 + c] = f2bf(tile[c][row]);
    }
  } else {
    size_t i = ((size_t)(blockIdx.x - 1024) * 256 + tid) * 4;
    f32x4 v = *(const f32x4*)(x + i);
    s16x4 o;
    o.x = (short)f2bf(v.x); o.y = (short)f2bf(v.y);
    o.z = (short)f2bf(v.z); o.w = (short)f2bf(v.w);
    *(s16x4*)(xb + i) = o;
  }
}

// --------------------------- 256x256 reg-pipelined 4-phase bf16 GEMM --------
// C[M][N] = A[M][1024] * Bt[N][1024]^T.
// MODE 0: N=3072 fused QKV -> q (softmax64), k (elu+1), v  (all bf16)
// MODE 1: N=1024 -> f32 out + bias
// 512 threads = 8 waves (2Mx4N); per-wave 128x64; BK=64 (two 32-K-halves).
// LDS 128KB: 2 buffers x [A-K0|A-K1|B-K0|B-K1] x 16KB.
// Reg-level read-ahead (R5) + L2-friendly per-XCD 4bm-chunk tile order (R6):
// working set per chunk = A 2MB + B-panel 0.5MB < 4MB XCD L2.
template <int MODE>
__global__ __launch_bounds__(512, 2) void gemm256(
    const u16* __restrict__ A, const u16* __restrict__ Bt,
    u16* __restrict__ dq, u16* __restrict__ dk, u16* __restrict__ dv,
    float* __restrict__ dO, const float* __restrict__ bias) {
  constexpr int K = 1024;
  constexpr int BNT = (MODE == 0) ? 12 : 4;   // N / 256
  constexpr int NT = K / 64;                  // 16 K-tiles
  extern __shared__ char lds[];

  const int tid = threadIdx.x;
  const int l = tid & 63;
  const int w = tid >> 6;
  const int wm = w >> 2;           // 0..1
  const int wn = w & 3;            // 0..3

  // per-XCD chunked mapping: 8 bm-rows/XCD in 2 groups of 4, bn-major inside
  const int xcd = (int)blockIdx.x & 7;
  const int idx = (int)blockIdx.x >> 3;
  const int g = idx / (4 * BNT);
  const int r2 = idx % (4 * BNT);
  const int bn = r2 >> 2;
  const int bm = xcd * 8 + g * 4 + (r2 & 3);
  const size_t arow0 = (size_t)bm * 256;
  const size_t brow0 = (size_t)bn * 256;

  int lrow[2], lcol[2];
#pragma unroll
  for (int i = 0; i < 2; ++i) {
    int lg = swz16k(tid * 16 + i * 8192);
    lrow[i] = lg >> 6;
    lcol[i] = (lg & 63) >> 1;
  }

  const int fr = l & 15;
  const int kswz = (((l >> 4) << 4)) ^ ((((fr >> 1) & 3)) << 4);

  auto STAGE = [&](int matsel, int kh, int tt) {   // matsel 0=A 1=B
    const int kbase = (tt & (NT - 1)) * 64 + kh * 32;   // wrap tail (harmless)
#pragma unroll
    for (int i = 0; i < 2; ++i) {
      const u16* src = (matsel == 0)
          ? A  + (arow0 + (size_t)lrow[i]) * K + kbase + lcol[i]
          : Bt + (brow0 + (size_t)lrow[i]) * K + kbase + lcol[i];
      char* dst = lds + ((tt & 1) * 65536 + (matsel * 2 + kh) * 16384 +
                         i * 8192 + w * 1024);
      __builtin_amdgcn_global_load_lds(
          (__attribute__((address_space(1))) const void*)src,
          (__attribute__((address_space(3))) void*)dst, 16, 0, 0);
    }
  };
  auto LDA = [&](int buf, int kh, int rowb) -> s16x8 {
    return *(const s16x8*)(lds + buf * 65536 + kh * 16384 + rowb * 64 + kswz);
  };
  auto LDB = [&](int buf, int kh, int rowb) -> s16x8 {
    return *(const s16x8*)(lds + buf * 65536 + 32768 + kh * 16384 + rowb * 64 + kswz);
  };

  f32x4 acc[8][4];
#pragma unroll
  for (int i = 0; i < 8; ++i)
#pragma unroll
    for (int j = 0; j < 4; ++j) acc[i][j] = {0.f, 0.f, 0.f, 0.f};

  // prologue: tile0 full, tile1 K0; drain tile0-K0 (12 outstanding -> 8)
  STAGE(0, 0, 0); STAGE(1, 0, 0); STAGE(0, 1, 0); STAGE(1, 1, 0);
  STAGE(0, 0, 1); STAGE(1, 0, 1);
  asm volatile("s_waitcnt vmcnt(8)" ::: "memory");
  __builtin_amdgcn_sched_barrier(0);
  __builtin_amdgcn_s_barrier();

  const int amb = wm * 128;
  const int bnb = wn * 64;
  s16x8 afA[4], afB[4], bfA[4], bfB[4];

  // pre-read ph1(t=0) fragments: kh0 of tile0
#pragma unroll
  for (int i = 0; i < 4; ++i) afA[i] = LDA(0, 0, amb + i * 16 + fr);
#pragma unroll
  for (int i = 0; i < 4; ++i) bfA[i] = LDB(0, 0, bnb + i * 16 + fr);

#define MFMA_BLK(ACCOFF, AF, BF)                                              \
  __builtin_amdgcn_s_setprio(1);                                              \
  _Pragma("unroll")                                                           \
  for (int mi = 0; mi < 4; ++mi)                                              \
    _Pragma("unroll")                                                         \
    for (int ni = 0; ni < 4; ++ni)                                            \
      acc[(ACCOFF) + mi][ni] = __builtin_amdgcn_mfma_f32_16x16x32_bf16(       \
          AF[mi], BF[ni], acc[(ACCOFF) + mi][ni], 0, 0, 0);                   \
  __builtin_amdgcn_s_setprio(0);

#define PHASES(BUF, T)                                                        \
  {                                                                           \
    const int buf = (BUF);                                                    \
    const int t = (T);                                                        \
    /* ph1: MFMA kh0 mi0-3 (afA x bfA); read afB=kh0 mi4-7; stage A-K1(t+1)*/ \
    STAGE(0, 1, t + 1);                                                       \
    _Pragma("unroll")                                                         \
    for (int i = 0; i < 4; ++i) afB[i] = LDA(buf, 0, amb + (4 + i) * 16 + fr);\
    MFMA_BLK(0, afA, bfA)                                                     \
    __builtin_amdgcn_s_barrier();                                             \
    /* ph2: MFMA kh0 mi4-7 (afB x bfA); vmcnt drains kh1(t); read afA,bfB */  \
    STAGE(1, 1, t + 1);                                                       \
    asm volatile("s_waitcnt vmcnt(8)" ::: "memory");                          \
    __builtin_amdgcn_sched_barrier(0);                                        \
    _Pragma("unroll")                                                         \
    for (int i = 0; i < 4; ++i) afA[i] = LDA(buf, 1, amb + i * 16 + fr);      \
    _Pragma("unroll")                                                         \
    for (int i = 0; i < 4; ++i) bfB[i] = LDB(buf, 1, bnb + i * 16 + fr);      \
    MFMA_BLK(4, afB, bfA)                                                     \
    __builtin_amdgcn_s_barrier();                                             \
    /* ph3: MFMA kh1 mi0-3 (afA x bfB); read afB=kh1 mi4-7; stage A-K0(t+2)*/ \
    STAGE(0, 0, t + 2);                                                       \
    _Pragma("unroll")                                                         \
    for (int i = 0; i < 4; ++i) afB[i] = LDA(buf, 1, amb + (4 + i) * 16 + fr);\
    MFMA_BLK(0, afA, bfB)                                                     \
    __builtin_amdgcn_s_barrier();                                             \
    /* ph4: MFMA kh1 mi4-7 (afB x bfB); vmcnt drains kh0(t+1); read next */   \
    STAGE(1, 0, t + 2);                                                       \
    asm volatile("s_waitcnt vmcnt(8)" ::: "memory");                          \
    __builtin_amdgcn_sched_barrier(0);                                        \
    _Pragma("unroll")                                                         \
    for (int i = 0; i < 4; ++i) afA[i] = LDA(buf ^ 1, 0, amb + i * 16 + fr);  \
    _Pragma("unroll")                                                         \
    for (int i = 0; i < 4; ++i) bfA[i] = LDB(buf ^ 1, 0, bnb + i * 16 + fr);  \
    MFMA_BLK(4, afB, bfB)                                                     \
    __builtin_amdgcn_s_barrier();                                             \
  }

#pragma unroll 1
  for (int th = 0; th < NT / 2; ++th) {
    PHASES(0, 2 * th)
    PHASES(1, 2 * th + 1)
  }
#undef PHASES
#undef MFMA_BLK

  // ---------------- epilogue: C row = (lane>>4)*4+j, col = lane&15 ----------
  const int r0 = (l >> 4) << 2;
  const int c0 = l & 15;
  if constexpr (MODE == 0) {
    const int mat = bn >> 2;                        // 0=q 1=k 2=v
    u16* dst = (mat == 0) ? dq : ((mat == 1) ? dk : dv);
    const size_t colbase = (size_t)(bn & 3) * 256 + (size_t)wn * 64;
    if (mat == 0) {
      // fused per-head softmax over the wave's 64 cols (= one head)
#pragma unroll
      for (int mi = 0; mi < 8; ++mi) {
#pragma unroll
        for (int j = 0; j < 4; ++j) {
          float v0 = acc[mi][0][j], v1 = acc[mi][1][j];
          float v2 = acc[mi][2][j], v3 = acc[mi][3][j];
          float m = fmaxf(fmaxf(v0, v1), fmaxf(v2, v3));
#pragma unroll
          for (int off = 1; off < 16; off <<= 1) m = fmaxf(m, __shfl_xor(m, off));
          float e0 = __expf(v0 - m), e1 = __expf(v1 - m);
          float e2 = __expf(v2 - m), e3 = __expf(v3 - m);
          float s = e0 + e1 + e2 + e3;
#pragma unroll
          for (int off = 1; off < 16; off <<= 1) s += __shfl_xor(s, off);
          float inv = 1.f / s;
          const size_t row = arow0 + wm * 128 + mi * 16 + r0 + j;
          u16* p = dst + row * DIMN + colbase + c0;
          p[0]  = f2bf(e0 * inv); p[16] = f2bf(e1 * inv);
          p[32] = f2bf(e2 * inv); p[48] = f2bf(e3 * inv);
        }
      }
    } else {
#pragma unroll
      for (int mi = 0; mi < 8; ++mi)
#pragma unroll
        for (int ni = 0; ni < 4; ++ni)
#pragma unroll
          for (int j = 0; j < 4; ++j) {
            const size_t row = arow0 + wm * 128 + mi * 16 + r0 + j;
            float v = acc[mi][ni][j];
            float r = (mat == 1) ? (v > 0.f ? v + 1.f : __expf(v)) : v;
            dst[row * DIMN + colbase + ni * 16 + c0] = f2bf(r);
          }
    }
  } else {
    // drain staging before reusing LDS for the C tile
    asm volatile("s_waitcnt vmcnt(0)" ::: "memory");
    __builtin_amdgcn_sched_barrier(0);
    __builtin_amdgcn_s_barrier();
    float* lf = (float*)lds;
#pragma unroll
    for (int half = 0; half < 2; ++half) {
      if (wm == half) {
#pragma unroll
        for (int mi = 0; mi < 8; ++mi)
#pragma unroll
          for (int ni = 0; ni < 4; ++ni) {
            const int col = wn * 64 + ni * 16 + c0;
            const float bv = bias[brow0 + col];
#pragma unroll
            for (int j = 0; j < 4; ++j) {
              const int row = mi * 16 + r0 + j;
              lf[row * 256 + (col ^ (((row >> 2) & 1) << 4))] =
                  acc[mi][ni][j] + bv;
            }
          }
      }
      __builtin_amdgcn_s_barrier();
#pragma unroll
      for (int i = 0; i < 16; ++i) {
        const int cid = tid + i * 512;
        const int r = cid >> 6;
        const int g2 = (cid & 63) * 4;
        const int pc = g2 ^ (((r >> 2) & 1) << 4);
        f32x4 vv = *(const f32x4*)&lf[r * 256 + pc];
        *(f32x4*)&dO[(arow0 + half * 128 + r) * DIMN + brow0 + g2] = vv;
      }
      __builtin_amdgcn_s_barrier();
    }
  }
}

// --------------------------- per-bucket context: C_u = k_u^T v_u ------------
// ctx out is bf16 now (f32 accumulation internally); ksum stays f32.
__global__ __launch_bounds__(256) void ctx_bucket_kern(const u16* __restrict__ kb,
                                                       const u16* __restrict__ vb,
                                                       u16* __restrict__ ctx,
                                                       float* __restrict__ ksum) {
  __shared__ float kl[4096];
  __shared__ float vl[4096];
  const int blk = blockIdx.x;
  const int u = blk & 63;
  const int bh = blk >> 6;
  const int b = bh >> 4, h = bh & 15;
  const size_t rowbase = (size_t)b * T_LEN + (size_t)u * 64;
  const int tid = threadIdx.x;
#pragma unroll
  for (int i = 0; i < 16; ++i) {
    int idx = i * 256 + tid;
    int n = idx >> 6, d = idx & 63;
    size_t g = (rowbase + n) * DIMN + (size_t)h * 64 + d;
    kl[idx] = bf2f(kb[g]);
    vl[idx] = bf2f(vb[g]);
  }
  __syncthreads();
  const int dq = (tid & 15) << 2;
  const int eq = (tid >> 4) << 2;
  float a[4][4] = {};
  float ks[4] = {};
  for (int n = 0; n < 64; ++n) {
    f32x4 kv = *(const f32x4*)&kl[n * 64 + dq];
    f32x4 vv = *(const f32x4*)&vl[n * 64 + eq];
#pragma unroll
    for (int i = 0; i < 4; ++i) {
      ks[i] += kv[i];
#pragma unroll
      for (int j = 0; j < 4; ++j) a[i][j] += kv[i] * vv[j];
    }
  }
  const size_t cbase = (size_t)blk * 4096;
#pragma unroll
  for (int i = 0; i < 4; ++i) {
    s16x4 o;
    o.x = (short)f2bf(a[i][0]); o.y = (short)f2bf(a[i][1]);
    o.z = (short)f2bf(a[i][2]); o.w = (short)f2bf(a[i][3]);
    *(s16x4*)&ctx[cbase + (size_t)(dq + i) * 64 + eq] = o;
  }
  if ((tid >> 4) == 0) {
    f32x4 o = {ks[0], ks[1], ks[2], ks[3]};
    *(f32x4*)&ksum[(size_t)blk * 64 + dq] = o;
  }
}

// ---------------- cumsum over u + normalize + shift, in place (bf16) --------
// thread owns (bh, d, e-quad); 65536 threads; f32 accumulators.
__global__ __launch_bounds__(256) void ctx_cumnorm_kern(u16* __restrict__ ctx,
                                                        const float* __restrict__ ksum) {
  const int tid = blockIdx.x * 256 + threadIdx.x;
  const int bh = tid >> 10;
  const int rem = tid & 1023;
  const int d = rem >> 4;
  const int e0 = (rem & 15) << 2;
  float c0 = 0.f, c1 = 0.f, c2 = 0.f, c3 = 0.f, accK = 0.f;
  for (int u = 0; u < 64; ++u) {
    const size_t base = ((size_t)(bh * 64 + u)) * 4096 + (size_t)d * 64 + e0;
    s16x4 cv4 = *(const s16x4*)&ctx[base];
    float kk = ksum[(size_t)(bh * 64 + u) * 64 + d];
    float x0 = bf2f((u16)cv4.x), x1 = bf2f((u16)cv4.y);
    float x2 = bf2f((u16)cv4.z), x3 = bf2f((u16)cv4.w);
    s16x4 o;
    if (u == 0) {
      o.x = 0; o.y = 0; o.z = 0; o.w = 0;
    } else {
      float inv = 1.f / (accK + 1e-6f);
      o.x = (short)f2bf(c0 * inv); o.y = (short)f2bf(c1 * inv);
      o.z = (short)f2bf(c2 * inv); o.w = (short)f2bf(c3 * inv);
    }
    *(s16x4*)&ctx[base] = o;                       // bucket u sees <= u-1
    c0 += x0; c1 += x1; c2 += x2; c3 += x3;
    accK += kk;
  }
}

// --------------------------- per-bucket attn: q_u @ ctx_u -------------------
__global__ __launch_bounds__(256) void attn_bucket_kern(const u16* __restrict__ qb,
                                                        const u16* __restrict__ ctx,
                                                        u16* __restrict__ attn) {
  __shared__ float qT[64 * 68];
  __shared__ float cl[4096];
  const int blk = blockIdx.x;
  const int u = blk & 63;
  const int bh = blk >> 6;
  const int b = bh >> 4, h = bh & 15;
  const size_t rowbase = (size_t)b * T_LEN + (size_t)u * 64;
  const int tid = threadIdx.x;
  const size_t cbase = (size_t)blk * 4096;
#pragma unroll
  for (int i = 0; i < 16; ++i) {
    int idx = i * 256 + tid;
    int n = idx >> 6, d = idx & 63;
    qT[d * 68 + n] = bf2f(qb[(rowbase + n) * DIMN + (size_t)h * 64 + d]);
  }
#pragma unroll
  for (int i = 0; i < 4; ++i) {
    int idx4 = (i * 256 + tid) * 4;
    s16x4 cv = *(const s16x4*)&ctx[cbase + idx4];
    cl[idx4]     = bf2f((u16)cv.x);
    cl[idx4 + 1] = bf2f((u16)cv.y);
    cl[idx4 + 2] = bf2f((u16)cv.z);
    cl[idx4 + 3] = bf2f((u16)cv.w);
  }
  __syncthreads();
  const int nq = (tid & 15) << 2;
  const int eq = (tid >> 4) << 2;
  float a[4][4] = {};
  for (int d = 0; d < 64; ++d) {
    f32x4 qv = *(const f32x4*)&qT[d * 68 + nq];
    f32x4 cv = *(const f32x4*)&cl[d * 64 + eq];
#pragma unroll
    for (int i = 0; i < 4; ++i)
#pragma unroll
      for (int j = 0; j < 4; ++j) a[i][j] += qv[i] * cv[j];
  }
#pragma unroll
  for (int i = 0; i < 4; ++i) {
    s16x4 o;
    o.x = (short)f2bf(a[i][0]); o.y = (short)f2bf(a[i][1]);
    o.z = (short)f2bf(a[i][2]); o.w = (short)f2bf(a[i][3]);
    *(s16x4*)&attn[(rowbase + nq + i) * DIMN + (size_t)h * 64 + eq] = o;
  }
}

// ---------------------------------------------------------------------------
extern "C" void kernel_launch(void* const* d_in, const int* in_sizes, int n_in,
                              void* d_out, int out_size, void* d_ws, size_t ws_size,
                              hipStream_t stream) {
  const float* x  = (const float*)d_in[0];
  const float* Wq = (const float*)d_in[1];
  const float* Wk = (const float*)d_in[2];
  const float* Wv = (const float*)d_in[3];
  const float* Wo = (const float*)d_in[4];
  const float* bo = (const float*)d_in[5];
  float* out = (float*)d_out;

  constexpr size_t SZ_XB = (size_t)MROWS * DIMN * 2;
  constexpr size_t SZ_WT = (size_t)DIMN * DIMN * 2;
  constexpr size_t SZ_CTX = (size_t)NB * NHEAD * 64 * 64 * 64 * 2;  // bf16
  char* ws = (char*)d_ws;
  u16*   xb   = (u16*)(ws);
  u16*   wqT  = (u16*)(ws + SZ_XB);          // wq/wk/wv/wo contiguous
  u16*   woT  = (u16*)(ws + SZ_XB + 3 * SZ_WT);
  u16*   qb   = (u16*)(ws + SZ_XB + 4 * SZ_WT);
  u16*   kb   = (u16*)(ws + 2 * SZ_XB + 4 * SZ_WT);
  u16*   vb   = (u16*)(ws + 3 * SZ_XB + 4 * SZ_WT);
  u16*   ctx  = (u16*)(ws + 4 * SZ_XB + 4 * SZ_WT);
  float* ksum = (float*)(ws + 4 * SZ_XB + 4 * SZ_WT + SZ_CTX);
  u16*   attn = xb;  // xb dead after QKV GEMM

  (void)hipFuncSetAttribute((const void*)gemm256<0>,
                            hipFuncAttributeMaxDynamicSharedMemorySize, 131072);
  (void)hipFuncSetAttribute((const void*)gemm256<1>,
                            hipFuncAttributeMaxDynamicSharedMemorySize, 131072);

  cvt_all_kern<<<1024 + MROWS * DIMN / 1024, 256, 0, stream>>>(x, Wq, Wk, Wv, Wo,
                                                               wqT, xb);

  // fused QKV: N = 3072, grid 64 x 12 = 768
  gemm256<0><<<768, 512, 131072, stream>>>(xb, wqT, qb, kb, vb, nullptr, nullptr);

  ctx_bucket_kern<<<NB * NHEAD * 64, 256, 0, stream>>>(kb, vb, ctx, ksum);
  ctx_cumnorm_kern<<<256, 256, 0, stream>>>(ctx, ksum);
  attn_bucket_kern<<<NB * NHEAD * 64, 256, 0, stream>>>(qb, ctx, attn);

  // output: N = 1024, grid 64 x 4 = 256
  gemm256<1><<<256, 512, 131072, stream>>>(attn, woT, nullptr, nullptr, nullptr, out, bo);
}

// Round 7
// 262.815 us; speedup vs baseline: 1.5755x; 1.0040x over previous
//
#include <hip/hip_runtime.h>

// ---------------------------------------------------------------------------
// LinearSelfAttention: B=4 T=4096 DIM=1024 H=16 E=64 BUCKET=64 U=64
// ---------------------------------------------------------------------------

#define T_LEN 4096
#define DIMN  1024
#define NHEAD 16
#define NB    4
#define MROWS (NB * T_LEN)   // 16384

typedef float f32x4 __attribute__((ext_vector_type(4)));
typedef short s16x8 __attribute__((ext_vector_type(8)));
typedef short s16x4 __attribute__((ext_vector_type(4)));
using u16 = unsigned short;

__device__ __forceinline__ u16 f2bf(float f) {
  unsigned int u = __float_as_uint(f);
  u += 0x7fffu + ((u >> 16) & 1u);   // RNE
  return (u16)(u >> 16);
}
__device__ __forceinline__ float bf2f(u16 h) {
  return __uint_as_float(((unsigned int)h) << 16);
}
// involution swizzle within a slot ([rows][32 bf16] = row*64B); key uses
// (off>>7)&3 = (row>>1)&3, unchanged by the XOR of byte-bits 4-5 -> involution.
__device__ __forceinline__ int swz16k(int off) {
  return off ^ (((off >> 7) & 3) << 4);
}

// ------------------- fused weight transpose+cast AND x cast ----------------
__global__ __launch_bounds__(256) void cvt_all_kern(const float* __restrict__ x,
                                                    const float* __restrict__ W0,
                                                    const float* __restrict__ W1,
                                                    const float* __restrict__ W2,
                                                    const float* __restrict__ W3,
                                                    u16* __restrict__ WT,
                                                    u16* __restrict__ xb) {
  __shared__ float tile[64][65];
  const int tid = threadIdx.x;
  if (blockIdx.x < 1024) {
    const int blk = blockIdx.x & 255;
    const int sel = blockIdx.x >> 8;
    const float* W = (sel == 0) ? W0 : (sel == 1) ? W1 : (sel == 2) ? W2 : W3;
    u16* dst = WT + (size_t)sel * DIMN * DIMN;
    const int k0 = (blk >> 4) << 6;
    const int n0 = (blk & 15) << 6;
    const int r = tid >> 6;
    const int c = tid & 63;
#pragma unroll
    for (int i = 0; i < 16; ++i) {
      int row = (i << 2) + r;
      tile[row][c] = W[(size_t)(k0 + row) * DIMN + n0 + c];
    }
    __syncthreads();
#pragma unroll
    for (int i = 0; i < 16; ++i) {
      int row = (i << 2) + r;
      dst[(size_t)(n0 + row) * DIMN + k0 + c] = f2bf(tile[c][row]);
    }
  } else {
    size_t i = ((size_t)(blockIdx.x - 1024) * 256 + tid) * 4;
    f32x4 v = *(const f32x4*)(x + i);
    s16x4 o;
    o.x = (short)f2bf(v.x); o.y = (short)f2bf(v.y);
    o.z = (short)f2bf(v.z); o.w = (short)f2bf(v.w);
    *(s16x4*)(xb + i) = o;
  }
}

// --------------------------- 128x256 2-blocks/CU bf16 GEMM ------------------
// C[M][N] = A[M][1024] * Bt[N][1024]^T.
// MODE 0: N=3072 fused QKV -> q (softmax64), k (elu+1), v  (all bf16)
// MODE 1: N=1024 -> f32 out + bias (direct stores)
// 512 threads = 8 waves (2Mx4N); per-wave 64x64 -> acc[4][4] (64 regs).
// BK=32. LDS static 48KB: 2 buf x [A 128x32 (8K) | B 256x32 (16K)].
// __launch_bounds__(512,4): 128-reg cap -> 16 waves/CU -> 2 blocks/CU.
// Protocol/K-step: stage(t+1) -> read frags(buf t) -> 16 MFMA ->
// vmcnt(0)+barrier. The drain is covered by the co-resident block (m97/m114).
template <int MODE>
__global__ __launch_bounds__(512, 4) void gemm_t(
    const u16* __restrict__ A, const u16* __restrict__ Bt,
    u16* __restrict__ dq, u16* __restrict__ dk, u16* __restrict__ dv,
    float* __restrict__ dO, const float* __restrict__ bias) {
  constexpr int K = 1024;
  constexpr int BNT = (MODE == 0) ? 12 : 4;   // N / 256
  constexpr int NT = K / 32;                  // 32 K-steps
  __shared__ char lds[49152];

  const int tid = threadIdx.x;
  const int l = tid & 63;
  const int w = tid >> 6;
  const int wm = w >> 2;           // 0..1 (64 rows each)
  const int wn = w & 3;            // 0..3 (64 cols each)

  // per-XCD chunked mapping: 16 bm-rows/XCD in 4 groups of 4, bn-major inside
  const int xcd = (int)blockIdx.x & 7;
  const int idx = (int)blockIdx.x >> 3;
  const int g = idx / (4 * BNT);
  const int r2 = idx % (4 * BNT);
  const int bn = r2 >> 2;
  const int bm = xcd * 16 + g * 4 + (r2 & 3);
  const size_t arow0 = (size_t)bm * 128;
  const size_t brow0 = (size_t)bn * 256;

  int lrow[2], lcol[2];
#pragma unroll
  for (int i = 0; i < 2; ++i) {
    int lg = swz16k(tid * 16 + i * 8192);
    lrow[i] = lg >> 6;
    lcol[i] = (lg & 63) >> 1;
  }

  const int fr = l & 15;
  const int kswz = (((l >> 4) << 4)) ^ ((((fr >> 1) & 3)) << 4);

  auto STAGE = [&](int matsel, int tt) {   // matsel 0=A (1 issue) 1=B (2)
    const int kbase = (tt & (NT - 1)) * 32;   // wrap tail (harmless)
#pragma unroll
    for (int i = 0; i < 2; ++i) {
      if (matsel == 0 && i == 1) break;
      const u16* src = (matsel == 0)
          ? A  + (arow0 + (size_t)lrow[i]) * K + kbase + lcol[i]
          : Bt + (brow0 + (size_t)lrow[i]) * K + kbase + lcol[i];
      char* dst = lds + ((tt & 1) * 24576 + matsel * 8192 + i * 8192 + tid * 16);
      __builtin_amdgcn_global_load_lds(
          (__attribute__((address_space(1))) const void*)src,
          (__attribute__((address_space(3))) void*)dst, 16, 0, 0);
    }
  };
  auto LDA = [&](int buf, int rowb) -> s16x8 {
    return *(const s16x8*)(lds + buf * 24576 + rowb * 64 + kswz);
  };
  auto LDB = [&](int buf, int rowb) -> s16x8 {
    return *(const s16x8*)(lds + buf * 24576 + 8192 + rowb * 64 + kswz);
  };

  f32x4 acc[4][4];
#pragma unroll
  for (int i = 0; i < 4; ++i)
#pragma unroll
    for (int j = 0; j < 4; ++j) acc[i][j] = {0.f, 0.f, 0.f, 0.f};

  // prologue: stage tile0, drain, barrier
  STAGE(0, 0); STAGE(1, 0);
  asm volatile("s_waitcnt vmcnt(0)" ::: "memory");
  __builtin_amdgcn_sched_barrier(0);
  __builtin_amdgcn_s_barrier();

  const int amb = wm * 64;
  const int bnb = wn * 64;
  s16x8 af[4], bf[4];

#define STEP(BUF, T)                                                          \
  {                                                                           \
    STAGE(0, (T) + 1);                                                        \
    STAGE(1, (T) + 1);                                                        \
    _Pragma("unroll")                                                         \
    for (int i = 0; i < 4; ++i) af[i] = LDA((BUF), amb + i * 16 + fr);        \
    _Pragma("unroll")                                                         \
    for (int i = 0; i < 4; ++i) bf[i] = LDB((BUF), bnb + i * 16 + fr);        \
    __builtin_amdgcn_s_setprio(1);                                            \
    _Pragma("unroll")                                                         \
    for (int mi = 0; mi < 4; ++mi)                                            \
      _Pragma("unroll")                                                       \
      for (int ni = 0; ni < 4; ++ni)                                          \
        acc[mi][ni] = __builtin_amdgcn_mfma_f32_16x16x32_bf16(                \
            af[mi], bf[ni], acc[mi][ni], 0, 0, 0);                            \
    __builtin_amdgcn_s_setprio(0);                                            \
    asm volatile("s_waitcnt vmcnt(0)" ::: "memory");                          \
    __builtin_amdgcn_sched_barrier(0);                                        \
    __builtin_amdgcn_s_barrier();                                             \
  }

#pragma unroll 1
  for (int th = 0; th < NT / 2; ++th) {
    STEP(0, 2 * th)
    STEP(1, 2 * th + 1)
  }
#undef STEP

  // ---------------- epilogue: C row = (lane>>4)*4+j, col = lane&15 ----------
  const int r0 = (l >> 4) << 2;
  const int c0 = l & 15;
  if constexpr (MODE == 0) {
    const int mat = bn >> 2;                        // 0=q 1=k 2=v
    u16* dst = (mat == 0) ? dq : ((mat == 1) ? dk : dv);
    const size_t colbase = (size_t)(bn & 3) * 256 + (size_t)wn * 64;
    if (mat == 0) {
      // fused per-head softmax over the wave's 64 cols (= one head)
#pragma unroll
      for (int mi = 0; mi < 4; ++mi) {
#pragma unroll
        for (int j = 0; j < 4; ++j) {
          float v0 = acc[mi][0][j], v1 = acc[mi][1][j];
          float v2 = acc[mi][2][j], v3 = acc[mi][3][j];
          float m = fmaxf(fmaxf(v0, v1), fmaxf(v2, v3));
#pragma unroll
          for (int off = 1; off < 16; off <<= 1) m = fmaxf(m, __shfl_xor(m, off));
          float e0 = __expf(v0 - m), e1 = __expf(v1 - m);
          float e2 = __expf(v2 - m), e3 = __expf(v3 - m);
          float s = e0 + e1 + e2 + e3;
#pragma unroll
          for (int off = 1; off < 16; off <<= 1) s += __shfl_xor(s, off);
          float inv = 1.f / s;
          const size_t row = arow0 + wm * 64 + mi * 16 + r0 + j;
          u16* p = dst + row * DIMN + colbase + c0;
          p[0]  = f2bf(e0 * inv); p[16] = f2bf(e1 * inv);
          p[32] = f2bf(e2 * inv); p[48] = f2bf(e3 * inv);
        }
      }
    } else {
#pragma unroll
      for (int mi = 0; mi < 4; ++mi)
#pragma unroll
        for (int ni = 0; ni < 4; ++ni)
#pragma unroll
          for (int j = 0; j < 4; ++j) {
            const size_t row = arow0 + wm * 64 + mi * 16 + r0 + j;
            float v = acc[mi][ni][j];
            float r = (mat == 1) ? (v > 0.f ? v + 1.f : __expf(v)) : v;
            dst[row * DIMN + colbase + ni * 16 + c0] = f2bf(r);
          }
    }
  } else {
#pragma unroll
    for (int mi = 0; mi < 4; ++mi)
#pragma unroll
      for (int ni = 0; ni < 4; ++ni) {
        const size_t col = brow0 + (size_t)wn * 64 + ni * 16 + c0;
        const float bv = bias[col];
#pragma unroll
        for (int j = 0; j < 4; ++j) {
          const size_t row = arow0 + wm * 64 + mi * 16 + r0 + j;
          dO[row * DIMN + col] = acc[mi][ni][j] + bv;
        }
      }
  }
}

// --------------------------- per-bucket context: C_u = k_u^T v_u ------------
// ctx out is bf16 (f32 accumulation internally); ksum stays f32.
__global__ __launch_bounds__(256) void ctx_bucket_kern(const u16* __restrict__ kb,
                                                       const u16* __restrict__ vb,
                                                       u16* __restrict__ ctx,
                                                       float* __restrict__ ksum) {
  __shared__ float kl[4096];
  __shared__ float vl[4096];
  const int blk = blockIdx.x;
  const int u = blk & 63;
  const int bh = blk >> 6;
  const int b = bh >> 4, h = bh & 15;
  const size_t rowbase = (size_t)b * T_LEN + (size_t)u * 64;
  const int tid = threadIdx.x;
#pragma unroll
  for (int i = 0; i < 16; ++i) {
    int idx = i * 256 + tid;
    int n = idx >> 6, d = idx & 63;
    size_t g = (rowbase + n) * DIMN + (size_t)h * 64 + d;
    kl[idx] = bf2f(kb[g]);
    vl[idx] = bf2f(vb[g]);
  }
  __syncthreads();
  const int dq = (tid & 15) << 2;
  const int eq = (tid >> 4) << 2;
  float a[4][4] = {};
  float ks[4] = {};
  for (int n = 0; n < 64; ++n) {
    f32x4 kv = *(const f32x4*)&kl[n * 64 + dq];
    f32x4 vv = *(const f32x4*)&vl[n * 64 + eq];
#pragma unroll
    for (int i = 0; i < 4; ++i) {
      ks[i] += kv[i];
#pragma unroll
      for (int j = 0; j < 4; ++j) a[i][j] += kv[i] * vv[j];
    }
  }
  const size_t cbase = (size_t)blk * 4096;
#pragma unroll
  for (int i = 0; i < 4; ++i) {
    s16x4 o;
    o.x = (short)f2bf(a[i][0]); o.y = (short)f2bf(a[i][1]);
    o.z = (short)f2bf(a[i][2]); o.w = (short)f2bf(a[i][3]);
    *(s16x4*)&ctx[cbase + (size_t)(dq + i) * 64 + eq] = o;
  }
  if ((tid >> 4) == 0) {
    f32x4 o = {ks[0], ks[1], ks[2], ks[3]};
    *(f32x4*)&ksum[(size_t)blk * 64 + dq] = o;
  }
}

// ---------------- cumsum over u + normalize + shift, in place (bf16) --------
__global__ __launch_bounds__(256) void ctx_cumnorm_kern(u16* __restrict__ ctx,
                                                        const float* __restrict__ ksum) {
  const int tid = blockIdx.x * 256 + threadIdx.x;
  const int bh = tid >> 10;
  const int rem = tid & 1023;
  const int d = rem >> 4;
  const int e0 = (rem & 15) << 2;
  float c0 = 0.f, c1 = 0.f, c2 = 0.f, c3 = 0.f, accK = 0.f;
  for (int u = 0; u < 64; ++u) {
    const size_t base = ((size_t)(bh * 64 + u)) * 4096 + (size_t)d * 64 + e0;
    s16x4 cv4 = *(const s16x4*)&ctx[base];
    float kk = ksum[(size_t)(bh * 64 + u) * 64 + d];
    float x0 = bf2f((u16)cv4.x), x1 = bf2f((u16)cv4.y);
    float x2 = bf2f((u16)cv4.z), x3 = bf2f((u16)cv4.w);
    s16x4 o;
    if (u == 0) {
      o.x = 0; o.y = 0; o.z = 0; o.w = 0;
    } else {
      float inv = 1.f / (accK + 1e-6f);
      o.x = (short)f2bf(c0 * inv); o.y = (short)f2bf(c1 * inv);
      o.z = (short)f2bf(c2 * inv); o.w = (short)f2bf(c3 * inv);
    }
    *(s16x4*)&ctx[base] = o;                       // bucket u sees <= u-1
    c0 += x0; c1 += x1; c2 += x2; c3 += x3;
    accK += kk;
  }
}

// --------------------------- per-bucket attn: q_u @ ctx_u -------------------
__global__ __launch_bounds__(256) void attn_bucket_kern(const u16* __restrict__ qb,
                                                        const u16* __restrict__ ctx,
                                                        u16* __restrict__ attn) {
  __shared__ float qT[64 * 68];
  __shared__ float cl[4096];
  const int blk = blockIdx.x;
  const int u = blk & 63;
  const int bh = blk >> 6;
  const int b = bh >> 4, h = bh & 15;
  const size_t rowbase = (size_t)b * T_LEN + (size_t)u * 64;
  const int tid = threadIdx.x;
  const size_t cbase = (size_t)blk * 4096;
#pragma unroll
  for (int i = 0; i < 16; ++i) {
    int idx = i * 256 + tid;
    int n = idx >> 6, d = idx & 63;
    qT[d * 68 + n] = bf2f(qb[(rowbase + n) * DIMN + (size_t)h * 64 + d]);
  }
#pragma unroll
  for (int i = 0; i < 4; ++i) {
    int idx4 = (i * 256 + tid) * 4;
    s16x4 cv = *(const s16x4*)&ctx[cbase + idx4];
    cl[idx4]     = bf2f((u16)cv.x);
    cl[idx4 + 1] = bf2f((u16)cv.y);
    cl[idx4 + 2] = bf2f((u16)cv.z);
    cl[idx4 + 3] = bf2f((u16)cv.w);
  }
  __syncthreads();
  const int nq = (tid & 15) << 2;
  const int eq = (tid >> 4) << 2;
  float a[4][4] = {};
  for (int d = 0; d < 64; ++d) {
    f32x4 qv = *(const f32x4*)&qT[d * 68 + nq];
    f32x4 cv = *(const f32x4*)&cl[d * 64 + eq];
#pragma unroll
    for (int i = 0; i < 4; ++i)
#pragma unroll
      for (int j = 0; j < 4; ++j) a[i][j] += qv[i] * cv[j];
  }
#pragma unroll
  for (int i = 0; i < 4; ++i) {
    s16x4 o;
    o.x = (short)f2bf(a[i][0]); o.y = (short)f2bf(a[i][1]);
    o.z = (short)f2bf(a[i][2]); o.w = (short)f2bf(a[i][3]);
    *(s16x4*)&attn[(rowbase + nq + i) * DIMN + (size_t)h * 64 + eq] = o;
  }
}

// ---------------------------------------------------------------------------
extern "C" void kernel_launch(void* const* d_in, const int* in_sizes, int n_in,
                              void* d_out, int out_size, void* d_ws, size_t ws_size,
                              hipStream_t stream) {
  const float* x  = (const float*)d_in[0];
  const float* Wq = (const float*)d_in[1];
  const float* Wk = (const float*)d_in[2];
  const float* Wv = (const float*)d_in[3];
  const float* Wo = (const float*)d_in[4];
  const float* bo = (const float*)d_in[5];
  float* out = (float*)d_out;

  constexpr size_t SZ_XB = (size_t)MROWS * DIMN * 2;
  constexpr size_t SZ_WT = (size_t)DIMN * DIMN * 2;
  constexpr size_t SZ_CTX = (size_t)NB * NHEAD * 64 * 64 * 64 * 2;  // bf16
  char* ws = (char*)d_ws;
  u16*   xb   = (u16*)(ws);
  u16*   wqT  = (u16*)(ws + SZ_XB);          // wq/wk/wv/wo contiguous
  u16*   woT  = (u16*)(ws + SZ_XB + 3 * SZ_WT);
  u16*   qb   = (u16*)(ws + SZ_XB + 4 * SZ_WT);
  u16*   kb   = (u16*)(ws + 2 * SZ_XB + 4 * SZ_WT);
  u16*   vb   = (u16*)(ws + 3 * SZ_XB + 4 * SZ_WT);
  u16*   ctx  = (u16*)(ws + 4 * SZ_XB + 4 * SZ_WT);
  float* ksum = (float*)(ws + 4 * SZ_XB + 4 * SZ_WT + SZ_CTX);
  u16*   attn = xb;  // xb dead after QKV GEMM

  cvt_all_kern<<<1024 + MROWS * DIMN / 1024, 256, 0, stream>>>(x, Wq, Wk, Wv, Wo,
                                                               wqT, xb);

  // fused QKV: N = 3072, grid 128 x 12 = 1536
  gemm_t<0><<<1536, 512, 0, stream>>>(xb, wqT, qb, kb, vb, nullptr, nullptr);

  ctx_bucket_kern<<<NB * NHEAD * 64, 256, 0, stream>>>(kb, vb, ctx, ksum);
  ctx_cumnorm_kern<<<256, 256, 0, stream>>>(ctx, ksum);
  attn_bucket_kern<<<NB * NHEAD * 64, 256, 0, stream>>>(qb, ctx, attn);

  // output: N = 1024, grid 128 x 4 = 512
  gemm_t<1><<<512, 512, 0, stream>>>(attn, woT, nullptr, nullptr, nullptr, out, bo);
}

// Round 8
// 259.143 us; speedup vs baseline: 1.5979x; 1.0142x over previous
//
#include <hip/hip_runtime.h>

// ---------------------------------------------------------------------------
// LinearSelfAttention: B=4 T=4096 DIM=1024 H=16 E=64 BUCKET=64 U=64
// ---------------------------------------------------------------------------

#define T_LEN 4096
#define DIMN  1024
#define NHEAD 16
#define NB    4
#define MROWS (NB * T_LEN)   // 16384

typedef float f32x4 __attribute__((ext_vector_type(4)));
typedef short s16x8 __attribute__((ext_vector_type(8)));
typedef short s16x4 __attribute__((ext_vector_type(4)));
using u16 = unsigned short;

__device__ __forceinline__ u16 f2bf(float f) {
  unsigned int u = __float_as_uint(f);
  u += 0x7fffu + ((u >> 16) & 1u);   // RNE
  return (u16)(u >> 16);
}
__device__ __forceinline__ float bf2f(u16 h) {
  return __uint_as_float(((unsigned int)h) << 16);
}

// ------------------- fused weight transpose+cast AND x cast ----------------
__global__ __launch_bounds__(256) void cvt_all_kern(const float* __restrict__ x,
                                                    const float* __restrict__ W0,
                                                    const float* __restrict__ W1,
                                                    const float* __restrict__ W2,
                                                    const float* __restrict__ W3,
                                                    u16* __restrict__ WT,
                                                    u16* __restrict__ xb) {
  __shared__ float tile[64][65];
  const int tid = threadIdx.x;
  if (blockIdx.x < 1024) {
    const int blk = blockIdx.x & 255;
    const int sel = blockIdx.x >> 8;
    const float* W = (sel == 0) ? W0 : (sel == 1) ? W1 : (sel == 2) ? W2 : W3;
    u16* dst = WT + (size_t)sel * DIMN * DIMN;
    const int k0 = (blk >> 4) << 6;
    const int n0 = (blk & 15) << 6;
    const int r = tid >> 6;
    const int c = tid & 63;
#pragma unroll
    for (int i = 0; i < 16; ++i) {
      int row = (i << 2) + r;
      tile[row][c] = W[(size_t)(k0 + row) * DIMN + n0 + c];
    }
    __syncthreads();
#pragma unroll
    for (int i = 0; i < 16; ++i) {
      int row = (i << 2) + r;
      dst[(size_t)(n0 + row) * DIMN + k0 + c] = f2bf(tile[c][row]);
    }
  } else {
    size_t i = ((size_t)(blockIdx.x - 1024) * 256 + tid) * 4;
    f32x4 v = *(const f32x4*)(x + i);
    s16x4 o;
    o.x = (short)f2bf(v.x); o.y = (short)f2bf(v.y);
    o.z = (short)f2bf(v.z); o.w = (short)f2bf(v.w);
    *(s16x4*)(xb + i) = o;
  }
}

// ------------------ 256x256 m201-style 8-phase bf16 GEMM --------------------
// C[M][N] = A[M][1024] * Bt[N][1024]^T.
// MODE 0: N=3072 fused QKV -> q (softmax64), k (elu+1), v  (all bf16)
// MODE 1: N=1024 -> f32 out + bias
// 512 thr = 8 waves (2Mx4N), per-wave 128x64, BK=64.
// LDS 128KB: 2 buf x [A-half0|A-half1|B-half0|B-half1] x 16KB (M/N-half
// staging, 128B row segments). Read swizzle: kByte ^= (row&7)<<4 (G4 recipe);
// staging keeps LDS linear and pre-swizzles the SOURCE column (rule #21).
// Phases = C-quadrants with register fragment reuse:
//  ph1 Q00: stage B0(t+1); read A0q(8)+B0q(4)   ph2 Q10: stage B1(t+1); read A1q(8)
//  ph3 Q01: stage A0(t+2); read B1q(4)          ph4 Q11: stage A1(t+2); 0 reads
// ONE vmcnt(4) per K-tile (end ph4): drains tile t+1's 4 halves exactly.
template <int MODE>
__global__ __launch_bounds__(512, 2) void gemm256(
    const u16* __restrict__ A, const u16* __restrict__ Bt,
    u16* __restrict__ dq, u16* __restrict__ dk, u16* __restrict__ dv,
    float* __restrict__ dO, const float* __restrict__ bias) {
  constexpr int K = 1024;
  constexpr int BNT = (MODE == 0) ? 12 : 4;   // N / 256
  constexpr int NT = K / 64;                  // 16 K-tiles
  extern __shared__ char lds[];

  const int tid = threadIdx.x;
  const int l = tid & 63;
  const int w = tid >> 6;
  const int wm = w >> 2;           // 0..1 (A-half = wm)
  const int wn = w & 3;            // 0..3 (B-half = wn>>1)

  // per-XCD chunked mapping (R6): 8 bm/XCD in 2 groups of 4, bn-major inside
  const int xcd = (int)blockIdx.x & 7;
  const int idx = (int)blockIdx.x >> 3;
  const int gg = idx / (4 * BNT);
  const int r2 = idx % (4 * BNT);
  const int bn = r2 >> 2;
  const int bm = xcd * 8 + gg * 4 + (r2 & 3);
  const size_t arow0 = (size_t)bm * 256;
  const size_t brow0 = (size_t)bn * 256;

  // staging decode: thread t, issue i -> dest byte d = i*8192 + t*16 (linear);
  // row = i*64 + (t>>3); src col pre-swizzled: ((t&7) ^ ((t>>3)&7))*16 bytes
  const int srow0 = tid >> 3;                 // + i*64
  const int scol = (((tid & 7) ^ ((tid >> 3) & 7)) << 3);   // in u16 elems

  auto STAGE = [&](int mat, int half, int tt) {
    const int kbase = (tt & (NT - 1)) * 64;
#pragma unroll
    for (int i = 0; i < 2; ++i) {
      const size_t grow = (mat == 0 ? arow0 : brow0) + half * 128 + i * 64 + srow0;
      const u16* src = (mat == 0 ? A : Bt) + grow * K + kbase + scol;
      char* dst = lds + ((tt & 1) * 65536 + mat * 32768 + half * 16384 +
                         i * 8192 + tid * 16);
      __builtin_amdgcn_global_load_lds(
          (__attribute__((address_space(1))) const void*)src,
          (__attribute__((address_space(3))) void*)dst, 16, 0, 0);
    }
  };

  const int fr = l & 15;
  const int kb16 = (l >> 4) << 4;   // byte offset of lane's 16B in a 64B k-half
  // A frag: half=wm, local row lr = miH*64+mi2*16+fr, kByte = kk*64 + kb16
  auto LDA = [&](int buf, int miH, int mi2, int kk) -> s16x8 {
    const int lr = miH * 64 + mi2 * 16 + fr;
    const int kByte = (kk * 64 + kb16) ^ ((lr & 7) << 4);
    return *(const s16x8*)(lds + buf * 65536 + wm * 16384 + lr * 128 + kByte);
  };
  auto LDB = [&](int buf, int ni, int kk) -> s16x8 {   // ni 0..3 global in wave
    const int lr = (wn & 1) * 64 + ni * 16 + fr;
    const int kByte = (kk * 64 + kb16) ^ ((lr & 7) << 4);
    return *(const s16x8*)(lds + buf * 65536 + 32768 + (wn >> 1) * 16384 +
                           lr * 128 + kByte);
  };

  f32x4 acc[8][4];
#pragma unroll
  for (int i = 0; i < 8; ++i)
#pragma unroll
    for (int j = 0; j < 4; ++j) acc[i][j] = {0.f, 0.f, 0.f, 0.f};

  // prologue: tile0 all 4 halves + tile1 A halves; drain tile0 (12 -> 4)
  STAGE(0, 0, 0); STAGE(0, 1, 0); STAGE(1, 0, 0); STAGE(1, 1, 0);
  STAGE(0, 0, 1); STAGE(0, 1, 1);
  asm volatile("s_waitcnt vmcnt(4)" ::: "memory");
  __builtin_amdgcn_sched_barrier(0);
  __builtin_amdgcn_s_barrier();

  s16x8 a0q[4][2], a1q[4][2], b0q[2][2], b1q[2][2];

#define MFMA16(AQ, NIOFF, BQ)                                                 \
  __builtin_amdgcn_s_setprio(1);                                              \
  _Pragma("unroll")                                                           \
  for (int mi = 0; mi < 4; ++mi)                                              \
    _Pragma("unroll")                                                         \
    for (int ni = 0; ni < 2; ++ni)                                            \
      _Pragma("unroll")                                                       \
      for (int kk = 0; kk < 2; ++kk)                                          \
        acc[(AQ##_OFF) + mi][(NIOFF) + ni] =                                  \
            __builtin_amdgcn_mfma_f32_16x16x32_bf16(                          \
                AQ[mi][kk], BQ[ni][kk], acc[(AQ##_OFF) + mi][(NIOFF) + ni],   \
                0, 0, 0);                                                     \
  __builtin_amdgcn_s_setprio(0);

#define KTILE(BUF, T)                                                         \
  {                                                                           \
    enum { a0q_OFF = 0, a1q_OFF = 4 };                                        \
    /* ph1 Q00 */                                                             \
    STAGE(1, 0, (T) + 1);                                                     \
    _Pragma("unroll")                                                         \
    for (int mi = 0; mi < 4; ++mi)                                            \
      _Pragma("unroll")                                                       \
      for (int kk = 0; kk < 2; ++kk) a0q[mi][kk] = LDA((BUF), 0, mi, kk);     \
    _Pragma("unroll")                                                         \
    for (int ni = 0; ni < 2; ++ni)                                            \
      _Pragma("unroll")                                                       \
      for (int kk = 0; kk < 2; ++kk) b0q[ni][kk] = LDB((BUF), ni, kk);        \
    __builtin_amdgcn_s_barrier();                                             \
    asm volatile("s_waitcnt lgkmcnt(0)" ::: "memory");                        \
    __builtin_amdgcn_sched_barrier(0);                                        \
    MFMA16(a0q, 0, b0q)                                                       \
    __builtin_amdgcn_s_barrier();                                             \
    /* ph2 Q10 */                                                             \
    STAGE(1, 1, (T) + 1);                                                     \
    _Pragma("unroll")                                                         \
    for (int mi = 0; mi < 4; ++mi)                                            \
      _Pragma("unroll")                                                       \
      for (int kk = 0; kk < 2; ++kk) a1q[mi][kk] = LDA((BUF), 1, mi, kk);     \
    __builtin_amdgcn_s_barrier();                                             \
    asm volatile("s_waitcnt lgkmcnt(0)" ::: "memory");                        \
    __builtin_amdgcn_sched_barrier(0);                                        \
    MFMA16(a1q, 0, b0q)                                                       \
    __builtin_amdgcn_s_barrier();                                             \
    /* ph3 Q01 */                                                             \
    STAGE(0, 0, (T) + 2);                                                     \
    _Pragma("unroll")                                                         \
    for (int ni = 0; ni < 2; ++ni)                                            \
      _Pragma("unroll")                                                       \
      for (int kk = 0; kk < 2; ++kk) b1q[ni][kk] = LDB((BUF), 2 + ni, kk);    \
    __builtin_amdgcn_s_barrier();                                             \
    asm volatile("s_waitcnt lgkmcnt(0)" ::: "memory");                        \
    __builtin_amdgcn_sched_barrier(0);                                        \
    MFMA16(a0q, 2, b1q)                                                       \
    __builtin_amdgcn_s_barrier();                                             \
    /* ph4 Q11: no reads */                                                   \
    STAGE(0, 1, (T) + 2);                                                     \
    __builtin_amdgcn_s_barrier();                                             \
    MFMA16(a1q, 2, b1q)                                                       \
    asm volatile("s_waitcnt vmcnt(4)" ::: "memory");                          \
    __builtin_amdgcn_sched_barrier(0);                                        \
    __builtin_amdgcn_s_barrier();                                             \
  }

#pragma unroll 1
  for (int th = 0; th < NT / 2; ++th) {
    KTILE(0, 2 * th)
    KTILE(1, 2 * th + 1)
  }
#undef KTILE
#undef MFMA16

  asm volatile("s_waitcnt vmcnt(0)" ::: "memory");
  __builtin_amdgcn_sched_barrier(0);
  __builtin_amdgcn_s_barrier();

  // ---------------- epilogue: C row = (lane>>4)*4+j, col = lane&15 ----------
  // acc[a][ni] -> row = wm*128 + (a>>2)*64 + (a&3)*16 + r0 + j
  const int r0 = (l >> 4) << 2;
  const int c0 = l & 15;
  if constexpr (MODE == 0) {
    const int mat = bn >> 2;                        // 0=q 1=k 2=v
    u16* dst = (mat == 0) ? dq : ((mat == 1) ? dk : dv);
    const size_t colbase = (size_t)(bn & 3) * 256 + (size_t)wn * 64;
    if (mat == 0) {
#pragma unroll
      for (int a = 0; a < 8; ++a) {
#pragma unroll
        for (int j = 0; j < 4; ++j) {
          float v0 = acc[a][0][j], v1 = acc[a][1][j];
          float v2 = acc[a][2][j], v3 = acc[a][3][j];
          float m = fmaxf(fmaxf(v0, v1), fmaxf(v2, v3));
#pragma unroll
          for (int off = 1; off < 16; off <<= 1) m = fmaxf(m, __shfl_xor(m, off));
          float e0 = __expf(v0 - m), e1 = __expf(v1 - m);
          float e2 = __expf(v2 - m), e3 = __expf(v3 - m);
          float s = e0 + e1 + e2 + e3;
#pragma unroll
          for (int off = 1; off < 16; off <<= 1) s += __shfl_xor(s, off);
          float inv = 1.f / s;
          const size_t row = arow0 + wm * 128 + (a >> 2) * 64 + (a & 3) * 16 + r0 + j;
          u16* p = dst + row * DIMN + colbase + c0;
          p[0]  = f2bf(e0 * inv); p[16] = f2bf(e1 * inv);
          p[32] = f2bf(e2 * inv); p[48] = f2bf(e3 * inv);
        }
      }
    } else {
#pragma unroll
      for (int a = 0; a < 8; ++a)
#pragma unroll
        for (int ni = 0; ni < 4; ++ni)
#pragma unroll
          for (int j = 0; j < 4; ++j) {
            const size_t row = arow0 + wm * 128 + (a >> 2) * 64 + (a & 3) * 16 + r0 + j;
            float v = acc[a][ni][j];
            float r = (mat == 1) ? (v > 0.f ? v + 1.f : __expf(v)) : v;
            dst[row * DIMN + colbase + ni * 16 + c0] = f2bf(r);
          }
    }
  } else {
#pragma unroll
    for (int a = 0; a < 8; ++a)
#pragma unroll
      for (int ni = 0; ni < 4; ++ni) {
        const size_t col = brow0 + (size_t)wn * 64 + ni * 16 + c0;
        const float bv = bias[col];
#pragma unroll
        for (int j = 0; j < 4; ++j) {
          const size_t row = arow0 + wm * 128 + (a >> 2) * 64 + (a & 3) * 16 + r0 + j;
          dO[row * DIMN + col] = acc[a][ni][j] + bv;
        }
      }
  }
}

// --------------------------- per-bucket context: C_u = k_u^T v_u ------------
__global__ __launch_bounds__(256) void ctx_bucket_kern(const u16* __restrict__ kb,
                                                       const u16* __restrict__ vb,
                                                       u16* __restrict__ ctx,
                                                       float* __restrict__ ksum) {
  __shared__ float kl[4096];
  __shared__ float vl[4096];
  const int blk = blockIdx.x;
  const int u = blk & 63;
  const int bh = blk >> 6;
  const int b = bh >> 4, h = bh & 15;
  const size_t rowbase = (size_t)b * T_LEN + (size_t)u * 64;
  const int tid = threadIdx.x;
#pragma unroll
  for (int i = 0; i < 16; ++i) {
    int idx = i * 256 + tid;
    int n = idx >> 6, d = idx & 63;
    size_t g = (rowbase + n) * DIMN + (size_t)h * 64 + d;
    kl[idx] = bf2f(kb[g]);
    vl[idx] = bf2f(vb[g]);
  }
  __syncthreads();
  const int dq = (tid & 15) << 2;
  const int eq = (tid >> 4) << 2;
  float a[4][4] = {};
  float ks[4] = {};
  for (int n = 0; n < 64; ++n) {
    f32x4 kv = *(const f32x4*)&kl[n * 64 + dq];
    f32x4 vv = *(const f32x4*)&vl[n * 64 + eq];
#pragma unroll
    for (int i = 0; i < 4; ++i) {
      ks[i] += kv[i];
#pragma unroll
      for (int j = 0; j < 4; ++j) a[i][j] += kv[i] * vv[j];
    }
  }
  const size_t cbase = (size_t)blk * 4096;
#pragma unroll
  for (int i = 0; i < 4; ++i) {
    s16x4 o;
    o.x = (short)f2bf(a[i][0]); o.y = (short)f2bf(a[i][1]);
    o.z = (short)f2bf(a[i][2]); o.w = (short)f2bf(a[i][3]);
    *(s16x4*)&ctx[cbase + (size_t)(dq + i) * 64 + eq] = o;
  }
  if ((tid >> 4) == 0) {
    f32x4 o = {ks[0], ks[1], ks[2], ks[3]};
    *(f32x4*)&ksum[(size_t)blk * 64 + dq] = o;
  }
}

// ---------------- cumsum over u + normalize + shift, in place (bf16) --------
__global__ __launch_bounds__(256) void ctx_cumnorm_kern(u16* __restrict__ ctx,
                                                        const float* __restrict__ ksum) {
  const int tid = blockIdx.x * 256 + threadIdx.x;
  const int bh = tid >> 10;
  const int rem = tid & 1023;
  const int d = rem >> 4;
  const int e0 = (rem & 15) << 2;
  float c0 = 0.f, c1 = 0.f, c2 = 0.f, c3 = 0.f, accK = 0.f;
  for (int u = 0; u < 64; ++u) {
    const size_t base = ((size_t)(bh * 64 + u)) * 4096 + (size_t)d * 64 + e0;
    s16x4 cv4 = *(const s16x4*)&ctx[base];
    float kk = ksum[(size_t)(bh * 64 + u) * 64 + d];
    float x0 = bf2f((u16)cv4.x), x1 = bf2f((u16)cv4.y);
    float x2 = bf2f((u16)cv4.z), x3 = bf2f((u16)cv4.w);
    s16x4 o;
    if (u == 0) {
      o.x = 0; o.y = 0; o.z = 0; o.w = 0;
    } else {
      float inv = 1.f / (accK + 1e-6f);
      o.x = (short)f2bf(c0 * inv); o.y = (short)f2bf(c1 * inv);
      o.z = (short)f2bf(c2 * inv); o.w = (short)f2bf(c3 * inv);
    }
    *(s16x4*)&ctx[base] = o;                       // bucket u sees <= u-1
    c0 += x0; c1 += x1; c2 += x2; c3 += x3;
    accK += kk;
  }
}

// --------------------------- per-bucket attn: q_u @ ctx_u -------------------
__global__ __launch_bounds__(256) void attn_bucket_kern(const u16* __restrict__ qb,
                                                        const u16* __restrict__ ctx,
                                                        u16* __restrict__ attn) {
  __shared__ float qT[64 * 68];
  __shared__ float cl[4096];
  const int blk = blockIdx.x;
  const int u = blk & 63;
  const int bh = blk >> 6;
  const int b = bh >> 4, h = bh & 15;
  const size_t rowbase = (size_t)b * T_LEN + (size_t)u * 64;
  const int tid = threadIdx.x;
  const size_t cbase = (size_t)blk * 4096;
#pragma unroll
  for (int i = 0; i < 16; ++i) {
    int idx = i * 256 + tid;
    int n = idx >> 6, d = idx & 63;
    qT[d * 68 + n] = bf2f(qb[(rowbase + n) * DIMN + (size_t)h * 64 + d]);
  }
#pragma unroll
  for (int i = 0; i < 4; ++i) {
    int idx4 = (i * 256 + tid) * 4;
    s16x4 cv = *(const s16x4*)&ctx[cbase + idx4];
    cl[idx4]     = bf2f((u16)cv.x);
    cl[idx4 + 1] = bf2f((u16)cv.y);
    cl[idx4 + 2] = bf2f((u16)cv.z);
    cl[idx4 + 3] = bf2f((u16)cv.w);
  }
  __syncthreads();
  const int nq = (tid & 15) << 2;
  const int eq = (tid >> 4) << 2;
  float a[4][4] = {};
  for (int d = 0; d < 64; ++d) {
    f32x4 qv = *(const f32x4*)&qT[d * 68 + nq];
    f32x4 cv = *(const f32x4*)&cl[d * 64 + eq];
#pragma unroll
    for (int i = 0; i < 4; ++i)
#pragma unroll
      for (int j = 0; j < 4; ++j) a[i][j] += qv[i] * cv[j];
  }
#pragma unroll
  for (int i = 0; i < 4; ++i) {
    s16x4 o;
    o.x = (short)f2bf(a[i][0]); o.y = (short)f2bf(a[i][1]);
    o.z = (short)f2bf(a[i][2]); o.w = (short)f2bf(a[i][3]);
    *(s16x4*)&attn[(rowbase + nq + i) * DIMN + (size_t)h * 64 + eq] = o;
  }
}

// ---------------------------------------------------------------------------
extern "C" void kernel_launch(void* const* d_in, const int* in_sizes, int n_in,
                              void* d_out, int out_size, void* d_ws, size_t ws_size,
                              hipStream_t stream) {
  const float* x  = (const float*)d_in[0];
  const float* Wq = (const float*)d_in[1];
  const float* Wk = (const float*)d_in[2];
  const float* Wv = (const float*)d_in[3];
  const float* Wo = (const float*)d_in[4];
  const float* bo = (const float*)d_in[5];
  float* out = (float*)d_out;

  constexpr size_t SZ_XB = (size_t)MROWS * DIMN * 2;
  constexpr size_t SZ_WT = (size_t)DIMN * DIMN * 2;
  constexpr size_t SZ_CTX = (size_t)NB * NHEAD * 64 * 64 * 64 * 2;  // bf16
  char* ws = (char*)d_ws;
  u16*   xb   = (u16*)(ws);
  u16*   wqT  = (u16*)(ws + SZ_XB);          // wq/wk/wv/wo contiguous
  u16*   woT  = (u16*)(ws + SZ_XB + 3 * SZ_WT);
  u16*   qb   = (u16*)(ws + SZ_XB + 4 * SZ_WT);
  u16*   kb   = (u16*)(ws + 2 * SZ_XB + 4 * SZ_WT);
  u16*   vb   = (u16*)(ws + 3 * SZ_XB + 4 * SZ_WT);
  u16*   ctx  = (u16*)(ws + 4 * SZ_XB + 4 * SZ_WT);
  float* ksum = (float*)(ws + 4 * SZ_XB + 4 * SZ_WT + SZ_CTX);
  u16*   attn = xb;  // xb dead after QKV GEMM

  (void)hipFuncSetAttribute((const void*)gemm256<0>,
                            hipFuncAttributeMaxDynamicSharedMemorySize, 131072);
  (void)hipFuncSetAttribute((const void*)gemm256<1>,
                            hipFuncAttributeMaxDynamicSharedMemorySize, 131072);

  cvt_all_kern<<<1024 + MROWS * DIMN / 1024, 256, 0, stream>>>(x, Wq, Wk, Wv, Wo,
                                                               wqT, xb);

  // fused QKV: N = 3072, grid 64 x 12 = 768
  gemm256<0><<<768, 512, 131072, stream>>>(xb, wqT, qb, kb, vb, nullptr, nullptr);

  ctx_bucket_kern<<<NB * NHEAD * 64, 256, 0, stream>>>(kb, vb, ctx, ksum);
  ctx_cumnorm_kern<<<256, 256, 0, stream>>>(ctx, ksum);
  attn_bucket_kern<<<NB * NHEAD * 64, 256, 0, stream>>>(qb, ctx, attn);

  // output: N = 1024, grid 64 x 4 = 256
  gemm256<1><<<256, 512, 131072, stream>>>(attn, woT, nullptr, nullptr, nullptr, out, bo);
}